// Round 4
// baseline (2988.610 us; speedup 1.0000x reference)
//
#include <hip/hip_runtime.h>
#include <math.h>

#define Bsz 1024
#define Npt 50
#define Hd 128
#define G4 512
#define Tt 50
#define NEGC 1000000000.0f
#define CTANH 10.0f

#define OFF_R 0
#define OFF_V 1024
#define OFF_LP 2048
#define OFF_A 2562048
#define OFF_C 2613248
#define OFF_P 2715648

// workspace float offsets (tables only; all scan state is LDS-resident)
#define WS_TG 0        // 128 float4: {Mg0, Mg1, vg, cg}
#define WS_TP 512      // 128 float4: {Mp0, Mp1, vp, cp}
#define WS_TQ 1024     // 128 float4: {Pg0, Pg1, cg@Wqp+cp, 0}
#define WS_TW 1536     // 128 float4: {We0, We1, bemb, 0}
#define WS_WQT 2048    // 16384: Wqg^T [hh][k]

__device__ __forceinline__ float fsig(float x) {
  return 1.0f / (1.0f + __expf(-x));
}

__device__ __forceinline__ float ftanh(float x) {
  float x2 = x * x;
  float p = x * (1.0f + x2 * (-0.33333333f + x2 * 0.13333333f));
  float e = __expf(2.0f * x);
  float tv = 1.0f - 2.0f * __builtin_amdgcn_rcpf(e + 1.0f);
  return (fabsf(x) < 0.1f) ? p : tv;
}

__device__ __forceinline__ float dpp_sum64(float x) {
  int v;
  v = __builtin_amdgcn_update_dpp(0, __float_as_int(x), 0x111, 0xf, 0xf, true);
  x += __int_as_float(v);
  v = __builtin_amdgcn_update_dpp(0, __float_as_int(x), 0x112, 0xf, 0xf, true);
  x += __int_as_float(v);
  v = __builtin_amdgcn_update_dpp(0, __float_as_int(x), 0x114, 0xf, 0xf, true);
  x += __int_as_float(v);
  v = __builtin_amdgcn_update_dpp(0, __float_as_int(x), 0x118, 0xf, 0xf, true);
  x += __int_as_float(v);
  v = __builtin_amdgcn_update_dpp(0, __float_as_int(x), 0x142, 0xf, 0xf, true);
  x += __int_as_float(v);
  v = __builtin_amdgcn_update_dpp(0, __float_as_int(x), 0x143, 0xf, 0xf, true);
  x += __int_as_float(v);
  return x;
}

__device__ __forceinline__ float xsum(float x) {
  #pragma unroll
  for (int off = 32; off >= 1; off >>= 1) x += __shfl_xor(x, off, 64);
  return x;
}
__device__ __forceinline__ float xmax(float x) {
  #pragma unroll
  for (int off = 32; off >= 1; off >>= 1) x = fmaxf(x, __shfl_xor(x, off, 64));
  return x;
}

__global__ __launch_bounds__(256) void k_pre(const float* __restrict__ Wemb,
                                             const float* __restrict__ bemb,
                                             const float* __restrict__ Wqg,
                                             const float* __restrict__ Wrg,
                                             const float* __restrict__ vg,
                                             const float* __restrict__ Wqp,
                                             const float* __restrict__ Wrp,
                                             const float* __restrict__ vp,
                                             float* __restrict__ ws) {
  __shared__ float mg_s[2][128], mp_s[2][128], cg_s[128], cp_s[128];
  __shared__ float pg_s[2][128], pc_s[128];
  int t = threadIdx.x, blk = blockIdx.x;
  if (blk > 0) {
    int f = (blk - 1) * 256 + t;
    ws[WS_WQT + f] = Wqg[(f & 127) * Hd + (f >> 7)];
    return;
  }
  int j = t >> 7, hh = t & 127;
  float ag = 0.f, ap = 0.f;
  for (int k = 0; k < 128; ++k) {
    float we = Wemb[j * 128 + k];
    ag = fmaf(we, Wrg[k * 128 + hh], ag);
    ap = fmaf(we, Wrp[k * 128 + hh], ap);
  }
  mg_s[j][hh] = ag; mp_s[j][hh] = ap;
  if (t < 128) {
    float cgv = 0.f, cpv = 0.f;
    for (int k = 0; k < 128; ++k) {
      float be = bemb[k];
      cgv = fmaf(be, Wrg[k * 128 + t], cgv);
      cpv = fmaf(be, Wrp[k * 128 + t], cpv);
    }
    cg_s[t] = cgv; cp_s[t] = cpv;
  }
  __syncthreads();
  float pg = 0.f;
  for (int k = 0; k < 128; ++k) pg = fmaf(mg_s[j][k], Wqp[k * 128 + hh], pg);
  pg_s[j][hh] = pg;
  if (t < 128) {
    float pcv = 0.f;
    for (int k = 0; k < 128; ++k) pcv = fmaf(cg_s[k], Wqp[k * 128 + t], pcv);
    pc_s[t] = pcv + cp_s[t];
  }
  __syncthreads();
  if (t < 128) {
    float4* w4 = (float4*)ws;
    w4[WS_TG / 4 + t] = make_float4(mg_s[0][t], mg_s[1][t], vg[t], cg_s[t]);
    w4[WS_TP / 4 + t] = make_float4(mp_s[0][t], mp_s[1][t], vp[t], cp_s[t]);
    w4[WS_TQ / 4 + t] = make_float4(pg_s[0][t], pg_s[1][t], pc_s[t], 0.f);
    w4[WS_TW / 4 + t] = make_float4(Wemb[t], Wemb[128 + t], bemb[t], 0.f);
  }
}

// Persistent kernel: 256 blocks x 1024 threads, 4 batch rows/block, full
// T=50 scan + epilogue inside. All state LDS-resident; no cross-block deps.
// gpart declared [10] slices (only 8 used) to push LDS past 80 KB -> HW can
// place only 1 block/CU -> even 256-block spread, near-lockstep phases, and
// the loop's L2 working set (weights only, ~640 KB/XCD) stays resident.
__global__ __launch_bounds__(1024) void k_mega(const float* __restrict__ ip,
                                               const float* __restrict__ dinit,
                                               const float* __restrict__ Wi,
                                               const float* __restrict__ Wh,
                                               const float* __restrict__ bl,
                                               const float* __restrict__ Wrc,
                                               const float* __restrict__ W1,
                                               const float* __restrict__ b1,
                                               const float* __restrict__ W2,
                                               const float* __restrict__ b2,
                                               const float* __restrict__ ws,
                                               float* __restrict__ out) {
  __shared__ __align__(16) float gpart[10][4][G4];    // 80 KB (8 used + pad)
  __shared__ __align__(16) float h_s[4][Hd];
  __shared__ __align__(16) float c_s[4][Hd];
  __shared__ __align__(16) float dec_s[4][Hd];
  __shared__ __align__(16) float qbuf[4][Hd];
  __shared__ __align__(16) float u_s[4][64];
  __shared__ __align__(16) float ip_s[4][Npt * 2];
  __shared__ __align__(16) float mask_s[4][Npt];
  __shared__ __align__(16) float ch_s[4][Npt * 2];

  int t = threadIdx.x, blk = blockIdx.x;
  int w = t >> 6, lane = t & 63;

  // ---- prologue: stage per-block state ----
  if (t < 200) ((float2*)ip_s)[t] = ((const float2*)ip)[blk * 200 + t];
  if (t < 512) {
    int r = t >> 7, hh = t & 127;
    h_s[r][hh] = 0.f;
    c_s[r][hh] = 0.f;
    dec_s[r][hh] = dinit[hh];
  }
  if (t < 200) ((float*)mask_s)[t] = 0.f;
  __syncthreads();

  int cr = w & 3, ni = w >> 2;
  int nIter = (ni == 3) ? 11 : 13;
  const float4* ws4 = (const float4*)ws;
  const float* wqt = ws + WS_WQT;

  for (int st = 0; st < Tt; ++st) {
    // ---- A1: gates partials: 8 k-chunks x 128 j-tiles(4 cols) x 4 rows ----
    {
      int kh = t >> 7, jt = t & 127;
      int k0 = kh * 16;
      float acc[4][4];
      #pragma unroll
      for (int r = 0; r < 4; ++r)
        #pragma unroll
        for (int c = 0; c < 4; ++c) acc[r][c] = 0.f;
      #pragma unroll
      for (int k4 = 0; k4 < 16; k4 += 4) {
        float xr[4][4], hr[4][4];
        #pragma unroll
        for (int r = 0; r < 4; ++r) {
          *(float4*)&xr[r][0] = *(const float4*)&dec_s[r][k0 + k4];
          *(float4*)&hr[r][0] = *(const float4*)&h_s[r][k0 + k4];
        }
        #pragma unroll
        for (int kk = 0; kk < 4; ++kk) {
          float wi4[4], wh4[4];
          *(float4*)wi4 = *(const float4*)&Wi[(k0 + k4 + kk) * G4 + jt * 4];
          *(float4*)wh4 = *(const float4*)&Wh[(k0 + k4 + kk) * G4 + jt * 4];
          #pragma unroll
          for (int r = 0; r < 4; ++r)
            #pragma unroll
            for (int c = 0; c < 4; ++c)
              acc[r][c] = fmaf(xr[r][kk], wi4[c], fmaf(hr[r][kk], wh4[c], acc[r][c]));
        }
      }
      #pragma unroll
      for (int r = 0; r < 4; ++r)
        *(float4*)&gpart[kh][r][jt * 4] = *(float4*)&acc[r][0];
    }
    __syncthreads();
    // ---- A2: combine + bias + LSTM cell ----
    if (t < 512) {
      int r = t >> 7, hh = t & 127;
      float gi = bl[hh], gf = bl[128 + hh], gg = bl[256 + hh], go = bl[384 + hh];
      #pragma unroll
      for (int kh = 0; kh < 8; ++kh) {
        gi += gpart[kh][r][hh];
        gf += gpart[kh][r][128 + hh];
        gg += gpart[kh][r][256 + hh];
        go += gpart[kh][r][384 + hh];
      }
      float c2 = fsig(gf) * c_s[r][hh] + fsig(gi) * ftanh(gg);
      float h2 = fsig(go) * ftanh(c2);
      c_s[r][hh] = c2;
      h_s[r][hh] = h2;
    }
    __syncthreads();
    // ---- B: q = h2 @ Wqg + cg ----
    if (t < 512) {
      int r = t >> 7, hh = t & 127;
      float a = 0.f;
      const float* wrow = wqt + hh * 128;
      #pragma unroll
      for (int k = 0; k < 128; k += 4) {
        float wv[4], hv[4];
        *(float4*)wv = *(const float4*)&wrow[k];
        *(float4*)hv = *(const float4*)&h_s[r][k];
        a = fmaf(hv[0], wv[0], fmaf(hv[1], wv[1], fmaf(hv[2], wv[2], fmaf(hv[3], wv[3], a))));
      }
      qbuf[r][hh] = a + ws4[WS_TG / 4 + hh].w;
    }
    __syncthreads();
    // ---- C: glimpse scores ----
    {
      float4 tA = ws4[WS_TG / 4 + lane];
      float4 tB = ws4[WS_TG / 4 + 64 + lane];
      float q0 = qbuf[cr][lane], q1 = qbuf[cr][64 + lane];
      for (int i = 0; i < nIter; ++i) {
        int n = ni * 13 + i;
        float2 pn = ((float2*)ip_s)[cr * Npt + n];
        float a0 = fmaf(pn.x, tA.x, fmaf(pn.y, tA.y, q0));
        float a1 = fmaf(pn.x, tB.x, fmaf(pn.y, tB.y, q1));
        float s = tA.z * ftanh(a0) + tB.z * ftanh(a1);
        s = dpp_sum64(s);
        if (lane == 63) u_s[cr][n] = s;
      }
    }
    __syncthreads();
    // ---- D: glimpse softmax -> (s0,s1) -> rank-2 pointer query ----
    if (w < 4) {
      int r = w;
      float2 ipn = make_float2(0.f, 0.f);
      float x = -INFINITY;
      if (lane < Npt) {
        ipn = ((float2*)ip_s)[r * Npt + lane];
        x = u_s[r][lane] - NEGC * mask_s[r][lane];
      }
      float m = xmax(x);
      float e = (lane < Npt) ? __expf(x - m) : 0.f;
      float ssum = xsum(e);
      float p = e / ssum;
      float s0 = xsum(p * ipn.x);
      float s1 = xsum(p * ipn.y);
      float4 tq0 = ws4[WS_TQ / 4 + lane];
      float4 tq1 = ws4[WS_TQ / 4 + 64 + lane];
      qbuf[r][lane]      = fmaf(s0, tq0.x, fmaf(s1, tq0.y, tq0.z));
      qbuf[r][64 + lane] = fmaf(s0, tq1.x, fmaf(s1, tq1.y, tq1.z));
    }
    __syncthreads();
    // ---- E: pointer scores ----
    {
      float4 tA = ws4[WS_TP / 4 + lane];
      float4 tB = ws4[WS_TP / 4 + 64 + lane];
      float q0 = qbuf[cr][lane], q1 = qbuf[cr][64 + lane];
      for (int i = 0; i < nIter; ++i) {
        int n = ni * 13 + i;
        float2 pn = ((float2*)ip_s)[cr * Npt + n];
        float a0 = fmaf(pn.x, tA.x, fmaf(pn.y, tA.y, q0));
        float a1 = fmaf(pn.x, tB.x, fmaf(pn.y, tB.y, q1));
        float s = tA.z * ftanh(a0) + tB.z * ftanh(a1);
        s = dpp_sum64(s);
        if (lane == 63) u_s[cr][n] = CTANH * ftanh(s);
      }
    }
    __syncthreads();
    // ---- F: pointer softmax / argmax / outputs / mask / dec_next ----
    if (w < 4) {
      int r = w, b = blk * 4 + r;
      float2 ipn = make_float2(0.f, 0.f);
      float x = -INFINITY;
      if (lane < Npt) {
        ipn = ((float2*)ip_s)[r * Npt + lane];
        x = u_s[r][lane] - NEGC * mask_s[r][lane];
      }
      float m = xmax(x);
      float sh = x - m;
      float e = (lane < Npt) ? __expf(sh) : 0.f;
      float ssum = xsum(e);
      float ls = __logf(ssum);
      float prob = e / ssum;
      if (lane < Npt) {
        out[OFF_LP + ((size_t)b * Tt + st) * Npt + lane] = sh - ls;
        out[OFF_P + ((size_t)b * Tt + st) * Npt + lane] = prob;
      }
      float pv = (lane < Npt) ? prob : -1.f;
      int idx = lane;
      #pragma unroll
      for (int off = 32; off >= 1; off >>= 1) {
        float po = __shfl_xor(pv, off, 64);
        int io = __shfl_xor(idx, off, 64);
        if (po > pv || (po == pv && io < idx)) { pv = po; idx = io; }
      }
      int a = idx;
      float p0a = __shfl(ipn.x, a, 64);
      float p1a = __shfl(ipn.y, a, 64);
      if (lane == 0) {
        out[OFF_A + (size_t)b * Tt + st] = (float)a;
        out[OFF_C + ((size_t)b * Tt + st) * 2 + 0] = p0a;
        out[OFF_C + ((size_t)b * Tt + st) * 2 + 1] = p1a;
        ((float2*)ch_s)[r * Npt + st] = make_float2(p0a, p1a);
        mask_s[r][a] = 1.0f;
      }
      float4 tw0 = ws4[WS_TW / 4 + lane];
      float4 tw1 = ws4[WS_TW / 4 + 64 + lane];
      dec_s[r][lane]      = fmaf(p0a, tw0.x, fmaf(p1a, tw0.y, tw0.z));
      dec_s[r][64 + lane] = fmaf(p0a, tw1.x, fmaf(p1a, tw1.y, tw1.z));
    }
    __syncthreads();
  }

  // ---- epilogue: critic (hy = dec_last@Wrc; v = relu(hy@W1+b1)@W2+b2), R ----
  float* scr = &gpart[0][0][0];
  if (t < 512) {
    int r = t >> 7, hh = t & 127;
    float a = 0.f;
    #pragma unroll 4
    for (int k = 0; k < 128; ++k) a = fmaf(dec_s[r][k], Wrc[k * 128 + hh], a);
    qbuf[r][hh] = a;
  }
  __syncthreads();
  if (t < 512) {
    int r = t >> 7, hh = t & 127;
    float a = b1[hh];
    #pragma unroll 4
    for (int k = 0; k < 128; ++k) a = fmaf(qbuf[r][k], W1[k * 128 + hh], a);
    scr[r * 128 + hh] = fmaxf(a, 0.f);
  }
  __syncthreads();
  if (w < 4) {
    int r = w, b = blk * 4 + r;
    float sv = scr[r * 128 + lane] * W2[lane] + scr[r * 128 + 64 + lane] * W2[64 + lane];
    sv = xsum(sv);
    if (lane == 0) out[OFF_V + b] = sv + b2[0];
    float rr = 0.f;
    if (lane < Npt) {
      float2 c0 = ((float2*)ch_s)[r * Npt + lane];
      float2 c1 = ((float2*)ch_s)[r * Npt + ((lane == Npt - 1) ? 0 : lane + 1)];
      float dx = c1.x - c0.x, dy = c1.y - c0.y;
      rr = sqrtf(dx * dx + dy * dy + 1e-10f);
    }
    rr = xsum(rr);
    if (lane == 0) out[OFF_R + b] = rr;
  }
}

extern "C" void kernel_launch(void* const* d_in, const int* in_sizes, int n_in,
                              void* d_out, int out_size, void* d_ws, size_t ws_size,
                              hipStream_t stream) {
  (void)in_sizes; (void)n_in; (void)out_size; (void)ws_size;
  const float* ip    = (const float*)d_in[0];
  const float* Wemb  = (const float*)d_in[1];
  const float* bemb  = (const float*)d_in[2];
  const float* dinit = (const float*)d_in[3];
  const float* Wi    = (const float*)d_in[4];
  const float* Wh    = (const float*)d_in[5];
  const float* bl    = (const float*)d_in[6];
  const float* Wqg   = (const float*)d_in[7];
  const float* Wrg   = (const float*)d_in[8];
  const float* vg    = (const float*)d_in[9];
  const float* Wqp   = (const float*)d_in[10];
  const float* Wrp   = (const float*)d_in[11];
  const float* vp    = (const float*)d_in[12];
  // d_in[13..16], d_in[18] dead: critic N=1 softmax == 1 => hy = e_c
  const float* Wrc   = (const float*)d_in[17];
  const float* W1    = (const float*)d_in[19];
  const float* b1    = (const float*)d_in[20];
  const float* W2    = (const float*)d_in[21];
  const float* b2    = (const float*)d_in[22];
  float* out = (float*)d_out;
  float* ws  = (float*)d_ws;

  k_pre<<<65, 256, 0, stream>>>(Wemb, bemb, Wqg, Wrg, vg, Wqp, Wrp, vp, ws);
  k_mega<<<256, 1024, 0, stream>>>(ip, dinit, Wi, Wh, bl, Wrc, W1, b1, W2, b2, ws, out);
}

// Round 5
// 906.730 us; speedup vs baseline: 3.2960x; 3.2960x over previous
//
#include <hip/hip_runtime.h>
#include <math.h>

#define Bsz 1024
#define Npt 50
#define Hd 128
#define G4 512
#define Tt 50
#define NEGC 1000000000.0f
#define CTANH 10.0f

#define OFF_R 0
#define OFF_V 1024
#define OFF_LP 2048
#define OFF_A 2562048
#define OFF_C 2613248
#define OFF_P 2715648

// ws float offsets (all tables; no bulk state)
#define WS_TG 0        // 128 float4 {Mg0, Mg1, vg, cg}
#define WS_TP 512      // 128 float4 {Mp0, Mp1, vp, cp}
#define WS_TQ 1024     // 128 float4 {Pg0, Pg1, cg@Wqp+cp, 0}
#define WS_A0 1536     // 512: We0@Wi
#define WS_A1 2048     // 512: We1@Wi
#define WS_A2 2560     // 512: bemb@Wi + bl
#define WS_A3 3072     // 512: dec_init@Wi + bl   (step 0)
#define WS_CT 3584     // 128 float4 {T0, T1, Tc(+b1), W2}  (critic, fully collapsed)

__device__ __forceinline__ float fsig(float x) {
  return 1.0f / (1.0f + __expf(-x));
}

__device__ __forceinline__ float ftanh(float x) {
  float x2 = x * x;
  float p = x * (1.0f + x2 * (-0.33333333f + x2 * 0.13333333f));
  float e = __expf(2.0f * x);
  float tv = 1.0f - 2.0f * __builtin_amdgcn_rcpf(e + 1.0f);
  return (fabsf(x) < 0.1f) ? p : tv;
}

__device__ __forceinline__ float dpp_sum64(float x) {
  int v;
  v = __builtin_amdgcn_update_dpp(0, __float_as_int(x), 0x111, 0xf, 0xf, true);
  x += __int_as_float(v);
  v = __builtin_amdgcn_update_dpp(0, __float_as_int(x), 0x112, 0xf, 0xf, true);
  x += __int_as_float(v);
  v = __builtin_amdgcn_update_dpp(0, __float_as_int(x), 0x114, 0xf, 0xf, true);
  x += __int_as_float(v);
  v = __builtin_amdgcn_update_dpp(0, __float_as_int(x), 0x118, 0xf, 0xf, true);
  x += __int_as_float(v);
  v = __builtin_amdgcn_update_dpp(0, __float_as_int(x), 0x142, 0xf, 0xf, true);
  x += __int_as_float(v);
  v = __builtin_amdgcn_update_dpp(0, __float_as_int(x), 0x143, 0xf, 0xf, true);
  x += __int_as_float(v);
  return x;
}

__device__ __forceinline__ float xsum(float x) {
  #pragma unroll
  for (int off = 32; off >= 1; off >>= 1) x += __shfl_xor(x, off, 64);
  return x;
}
__device__ __forceinline__ float xmax(float x) {
  #pragma unroll
  for (int off = 32; off >= 1; off >>= 1) x = fmaxf(x, __shfl_xor(x, off, 64));
  return x;
}

// One block, 512 threads: all rank-2 tables + collapsed critic tables.
__global__ __launch_bounds__(512) void k_pre(const float* __restrict__ Wemb,
                                             const float* __restrict__ bemb,
                                             const float* __restrict__ dinit,
                                             const float* __restrict__ Wi,
                                             const float* __restrict__ bl,
                                             const float* __restrict__ Wqp,
                                             const float* __restrict__ Wrg,
                                             const float* __restrict__ Wrp,
                                             const float* __restrict__ vg,
                                             const float* __restrict__ vp,
                                             const float* __restrict__ Wrc,
                                             const float* __restrict__ W1,
                                             const float* __restrict__ b1,
                                             const float* __restrict__ W2,
                                             float* __restrict__ ws) {
  __shared__ float mg_s[2][128], mp_s[2][128], cg_s[128], cp_s[128];
  __shared__ float pg_s[2][128], pc_s[128];
  __shared__ float r0_s[128], r1_s[128], rc_s[128];
  int t = threadIdx.x;
  if (t < 256) {
    int j = t >> 7, hh = t & 127;
    float ag = 0.f, ap = 0.f;
    for (int k = 0; k < 128; ++k) {
      float we = Wemb[j * 128 + k];
      ag = fmaf(we, Wrg[k * 128 + hh], ag);
      ap = fmaf(we, Wrp[k * 128 + hh], ap);
    }
    mg_s[j][hh] = ag; mp_s[j][hh] = ap;
  } else if (t < 384) {
    int hh = t & 127;
    float cgv = 0.f, cpv = 0.f;
    for (int k = 0; k < 128; ++k) {
      float be = bemb[k];
      cgv = fmaf(be, Wrg[k * 128 + hh], cgv);
      cpv = fmaf(be, Wrp[k * 128 + hh], cpv);
    }
    cg_s[hh] = cgv; cp_s[hh] = cpv;
  } else {
    int hh = t & 127;
    float a0 = 0.f, a1 = 0.f, ac = 0.f;
    for (int k = 0; k < 128; ++k) {
      float wr = Wrc[k * 128 + hh];
      a0 = fmaf(Wemb[k], wr, a0);
      a1 = fmaf(Wemb[128 + k], wr, a1);
      ac = fmaf(bemb[k], wr, ac);
    }
    r0_s[hh] = a0; r1_s[hh] = a1; rc_s[hh] = ac;
  }
  __syncthreads();
  if (t < 256) {
    int j = t >> 7, hh = t & 127;
    float pg = 0.f;
    for (int k = 0; k < 128; ++k) pg = fmaf(mg_s[j][k], Wqp[k * 128 + hh], pg);
    pg_s[j][hh] = pg;
  } else if (t < 384) {
    int hh = t & 127;
    float pcv = 0.f;
    for (int k = 0; k < 128; ++k) pcv = fmaf(cg_s[k], Wqp[k * 128 + hh], pcv);
    pc_s[hh] = pcv + cp_s[hh];
  } else {
    int hh = t & 127;
    float t0 = 0.f, t1 = 0.f, tc = 0.f;
    for (int k = 0; k < 128; ++k) {
      float w1 = W1[k * 128 + hh];
      t0 = fmaf(r0_s[k], w1, t0);
      t1 = fmaf(r1_s[k], w1, t1);
      tc = fmaf(rc_s[k], w1, tc);
    }
    float4* w4 = (float4*)ws;
    w4[WS_CT / 4 + hh] = make_float4(t0, t1, tc + b1[hh], W2[hh]);
  }
  __syncthreads();
  if (t < 128) {
    float4* w4 = (float4*)ws;
    w4[WS_TG / 4 + t] = make_float4(mg_s[0][t], mg_s[1][t], vg[t], cg_s[t]);
    w4[WS_TP / 4 + t] = make_float4(mp_s[0][t], mp_s[1][t], vp[t], cp_s[t]);
    w4[WS_TQ / 4 + t] = make_float4(pg_s[0][t], pg_s[1][t], pc_s[t], 0.f);
  }
  // rank-2 x@Wi tables, one column per thread
  {
    int j = t;
    float a0 = 0.f, a1 = 0.f, a2 = 0.f, a3 = 0.f;
    for (int k = 0; k < 128; ++k) {
      float wi = Wi[k * G4 + j];
      a0 = fmaf(Wemb[k], wi, a0);
      a1 = fmaf(Wemb[128 + k], wi, a1);
      a2 = fmaf(bemb[k], wi, a2);
      a3 = fmaf(dinit[k], wi, a3);
    }
    ws[WS_A0 + j] = a0;
    ws[WS_A1 + j] = a1;
    ws[WS_A2 + j] = a2 + bl[j];
    ws[WS_A3 + j] = a3 + bl[j];
  }
}

// Persistent: 256 blocks x 512 threads, 4 rows/block, T=50 + epilogue inside.
// Wh lives in VGPRs (128/thread); Wqg + all tables in LDS. The step loop has
// ZERO global reads -> block drift is harmless, no L2 thrash possible.
__global__ __launch_bounds__(512, 2) void k_mega(const float* __restrict__ ip,
                                                 const float* __restrict__ Wh,
                                                 const float* __restrict__ Wqg,
                                                 const float* __restrict__ b2,
                                                 const float* __restrict__ ws,
                                                 float* __restrict__ out) {
  __shared__ __align__(16) float wq_s[Hd * Hd];       // 64 KB
  __shared__ __align__(16) float gpart[4][4][G4];     // 32 KB
  __shared__ __align__(16) float qpart[4][4][Hd];     // 8 KB
  __shared__ __align__(16) float h_s[4][Hd];
  __shared__ __align__(16) float c_s[4][Hd];
  __shared__ __align__(16) float qbuf[4][Hd];
  __shared__ __align__(16) float tg_s[G4];
  __shared__ __align__(16) float tp_s[G4];
  __shared__ __align__(16) float tq_s[G4];
  __shared__ __align__(16) float ct_s[G4];
  __shared__ __align__(16) float a0_s[G4], a1_s[G4], a2_s[G4], a3_s[G4];
  __shared__ __align__(16) float u_s[4][64];
  __shared__ __align__(16) float ip_s[4][Npt * 2];
  __shared__ float mask_s[4][Npt];
  __shared__ float ch_s[4][Npt * 2];
  __shared__ float sel_s[4][2];

  int t = threadIdx.x, blk = blockIdx.x;
  int w = t >> 6, lane = t & 63;
  int kh = t >> 7, jt = t & 127;     // A1 layout: 4 k-chunks x 128 col-quads
  int r4 = t >> 7, hh = t & 127;     // per-(row,hh) layout

  // ---- Wh -> registers: thread owns Wh[kh*32 .. +32)[jt*4 .. +4) ----
  float4 wv[32];
  #pragma unroll
  for (int j = 0; j < 32; ++j)
    wv[j] = *(const float4*)&Wh[(kh * 32 + j) * G4 + jt * 4];

  // ---- stage Wqg + tables + per-block state ----
  for (int i = t; i < Hd * Hd / 4; i += 512)
    ((float4*)wq_s)[i] = ((const float4*)Wqg)[i];
  if (t < 128) {
    ((float4*)tg_s)[t] = ((const float4*)(ws + WS_TG))[t];
    ((float4*)tp_s)[t] = ((const float4*)(ws + WS_TP))[t];
    ((float4*)tq_s)[t] = ((const float4*)(ws + WS_TQ))[t];
    ((float4*)ct_s)[t] = ((const float4*)(ws + WS_CT))[t];
  } else if (t < 256) {
    int i = t - 128;
    ((float4*)a0_s)[i] = ((const float4*)(ws + WS_A0))[i];
    ((float4*)a1_s)[i] = ((const float4*)(ws + WS_A1))[i];
    ((float4*)a2_s)[i] = ((const float4*)(ws + WS_A2))[i];
    ((float4*)a3_s)[i] = ((const float4*)(ws + WS_A3))[i];
  }
  if (t < 200) {
    ((float2*)ip_s)[t] = ((const float2*)ip)[blk * 200 + t];
    ((float*)mask_s)[t] = 0.f;
  }
  h_s[r4][hh] = 0.f;
  c_s[r4][hh] = 0.f;
  __syncthreads();

  int cr = w & 3, ni = w >> 2;       // score phases: 2 waves per row, 25 n each

  for (int st = 0; st < Tt; ++st) {
    // ---- A1: h @ Wh partials from register-resident weights ----
    {
      float acc[4][4];
      #pragma unroll
      for (int r = 0; r < 4; ++r)
        #pragma unroll
        for (int c = 0; c < 4; ++c) acc[r][c] = 0.f;
      #pragma unroll
      for (int jj = 0; jj < 32; jj += 4) {
        float h4[4][4];
        #pragma unroll
        for (int r = 0; r < 4; ++r)
          *(float4*)&h4[r][0] = *(const float4*)&h_s[r][kh * 32 + jj];
        #pragma unroll
        for (int kk = 0; kk < 4; ++kk) {
          float4 wj = wv[jj + kk];
          #pragma unroll
          for (int r = 0; r < 4; ++r) {
            acc[r][0] = fmaf(h4[r][kk], wj.x, acc[r][0]);
            acc[r][1] = fmaf(h4[r][kk], wj.y, acc[r][1]);
            acc[r][2] = fmaf(h4[r][kk], wj.z, acc[r][2]);
            acc[r][3] = fmaf(h4[r][kk], wj.w, acc[r][3]);
          }
        }
      }
      #pragma unroll
      for (int r = 0; r < 4; ++r)
        *(float4*)&gpart[kh][r][jt * 4] = *(float4*)&acc[r][0];
    }
    __syncthreads();
    // ---- A2: combine + rank-2 x-part + LSTM cell ----
    {
      int r = r4;
      float p0 = sel_s[r][0], p1 = sel_s[r][1];
      float g[4];
      #pragma unroll
      for (int gi = 0; gi < 4; ++gi) {
        int j = gi * 128 + hh;
        float x = (st == 0) ? a3_s[j]
                            : fmaf(p0, a0_s[j], fmaf(p1, a1_s[j], a2_s[j]));
        x += gpart[0][r][j] + gpart[1][r][j] + gpart[2][r][j] + gpart[3][r][j];
        g[gi] = x;
      }
      float c2 = fsig(g[1]) * c_s[r][hh] + fsig(g[0]) * ftanh(g[2]);
      float h2 = fsig(g[3]) * ftanh(c2);
      c_s[r][hh] = c2;
      h_s[r][hh] = h2;
    }
    __syncthreads();
    // ---- B: qpart = h2 @ Wqg (k-split 4-way) ----
    {
      int ks = kh;
      float acc4[4] = {0.f, 0.f, 0.f, 0.f};
      #pragma unroll 8
      for (int k = ks * 32; k < ks * 32 + 32; ++k) {
        float wqv = wq_s[k * Hd + hh];
        acc4[0] = fmaf(h_s[0][k], wqv, acc4[0]);
        acc4[1] = fmaf(h_s[1][k], wqv, acc4[1]);
        acc4[2] = fmaf(h_s[2][k], wqv, acc4[2]);
        acc4[3] = fmaf(h_s[3][k], wqv, acc4[3]);
      }
      #pragma unroll
      for (int r = 0; r < 4; ++r) qpart[ks][r][hh] = acc4[r];
    }
    __syncthreads();
    // ---- C: glimpse scores u[n] = vg . tanh(eg(n) + q) ----
    {
      float4 tA = ((float4*)tg_s)[lane];
      float4 tB = ((float4*)tg_s)[64 + lane];
      float q0 = qpart[0][cr][lane] + qpart[1][cr][lane]
               + qpart[2][cr][lane] + qpart[3][cr][lane] + tA.w;
      float q1 = qpart[0][cr][64 + lane] + qpart[1][cr][64 + lane]
               + qpart[2][cr][64 + lane] + qpart[3][cr][64 + lane] + tB.w;
      #pragma unroll 5
      for (int i = 0; i < 25; ++i) {
        int n = ni * 25 + i;
        float2 pn = ((float2*)ip_s)[cr * Npt + n];
        float a0 = fmaf(pn.x, tA.x, fmaf(pn.y, tA.y, q0));
        float a1 = fmaf(pn.x, tB.x, fmaf(pn.y, tB.y, q1));
        float s = tA.z * ftanh(a0) + tB.z * ftanh(a1);
        s = dpp_sum64(s);
        if (lane == 63) u_s[cr][n] = s;
      }
    }
    __syncthreads();
    // ---- D: glimpse softmax -> (s0,s1) -> rank-2 pointer query ----
    if (w < 4) {
      int r = w;
      float2 ipn = make_float2(0.f, 0.f);
      float x = -INFINITY;
      if (lane < Npt) {
        ipn = ((float2*)ip_s)[r * Npt + lane];
        x = u_s[r][lane] - NEGC * mask_s[r][lane];
      }
      float m = xmax(x);
      float e = (lane < Npt) ? __expf(x - m) : 0.f;
      float ssum = xsum(e);
      float p = e / ssum;
      float s0 = xsum(p * ipn.x);
      float s1 = xsum(p * ipn.y);
      float4 tq0 = ((float4*)tq_s)[lane];
      float4 tq1 = ((float4*)tq_s)[64 + lane];
      qbuf[r][lane]      = fmaf(s0, tq0.x, fmaf(s1, tq0.y, tq0.z));
      qbuf[r][64 + lane] = fmaf(s0, tq1.x, fmaf(s1, tq1.y, tq1.z));
    }
    __syncthreads();
    // ---- E: pointer scores -> logit = C*tanh(u2) ----
    {
      float4 tA = ((float4*)tp_s)[lane];
      float4 tB = ((float4*)tp_s)[64 + lane];
      float q0 = qbuf[cr][lane], q1 = qbuf[cr][64 + lane];
      #pragma unroll 5
      for (int i = 0; i < 25; ++i) {
        int n = ni * 25 + i;
        float2 pn = ((float2*)ip_s)[cr * Npt + n];
        float a0 = fmaf(pn.x, tA.x, fmaf(pn.y, tA.y, q0));
        float a1 = fmaf(pn.x, tB.x, fmaf(pn.y, tB.y, q1));
        float s = tA.z * ftanh(a0) + tB.z * ftanh(a1);
        s = dpp_sum64(s);
        if (lane == 63) u_s[cr][n] = CTANH * ftanh(s);
      }
    }
    __syncthreads();
    // ---- F: pointer softmax / argmax / outputs / mask / next coords ----
    if (w < 4) {
      int r = w, b = blk * 4 + r;
      float2 ipn = make_float2(0.f, 0.f);
      float x = -INFINITY;
      if (lane < Npt) {
        ipn = ((float2*)ip_s)[r * Npt + lane];
        x = u_s[r][lane] - NEGC * mask_s[r][lane];
      }
      float m = xmax(x);
      float sh = x - m;
      float e = (lane < Npt) ? __expf(sh) : 0.f;
      float ssum = xsum(e);
      float ls = __logf(ssum);
      float prob = e / ssum;
      if (lane < Npt) {
        out[OFF_LP + ((size_t)b * Tt + st) * Npt + lane] = sh - ls;
        out[OFF_P + ((size_t)b * Tt + st) * Npt + lane] = prob;
      }
      float pv = (lane < Npt) ? prob : -1.f;
      int idx = lane;
      #pragma unroll
      for (int off = 32; off >= 1; off >>= 1) {
        float po = __shfl_xor(pv, off, 64);
        int io = __shfl_xor(idx, off, 64);
        if (po > pv || (po == pv && io < idx)) { pv = po; idx = io; }
      }
      int a = idx;
      float p0a = __shfl(ipn.x, a, 64);
      float p1a = __shfl(ipn.y, a, 64);
      if (lane == 0) {
        out[OFF_A + (size_t)b * Tt + st] = (float)a;
        out[OFF_C + ((size_t)b * Tt + st) * 2 + 0] = p0a;
        out[OFF_C + ((size_t)b * Tt + st) * 2 + 1] = p1a;
        ((float2*)ch_s)[r * Npt + st] = make_float2(p0a, p1a);
        mask_s[r][a] = 1.0f;
        sel_s[r][0] = p0a;
        sel_s[r][1] = p1a;
      }
    }
    __syncthreads();
  }

  // ---- epilogue: critic via collapsed tables + tour length ----
  if (w < 4) {
    int r = w, b = blk * 4 + r;
    float p0 = sel_s[r][0], p1 = sel_s[r][1];
    float4 ct0 = ((float4*)ct_s)[lane];
    float4 ct1 = ((float4*)ct_s)[64 + lane];
    float t1a = fmaxf(fmaf(p0, ct0.x, fmaf(p1, ct0.y, ct0.z)), 0.f);
    float t1b = fmaxf(fmaf(p0, ct1.x, fmaf(p1, ct1.y, ct1.z)), 0.f);
    float sv = xsum(t1a * ct0.w + t1b * ct1.w);
    if (lane == 0) out[OFF_V + b] = sv + b2[0];
    float rr = 0.f;
    if (lane < Npt) {
      float2 c0 = ((float2*)ch_s)[r * Npt + lane];
      float2 c1 = ((float2*)ch_s)[r * Npt + ((lane == Npt - 1) ? 0 : lane + 1)];
      float dx = c1.x - c0.x, dy = c1.y - c0.y;
      rr = sqrtf(dx * dx + dy * dy + 1e-10f);
    }
    rr = xsum(rr);
    if (lane == 0) out[OFF_R + b] = rr;
  }
}

extern "C" void kernel_launch(void* const* d_in, const int* in_sizes, int n_in,
                              void* d_out, int out_size, void* d_ws, size_t ws_size,
                              hipStream_t stream) {
  (void)in_sizes; (void)n_in; (void)out_size; (void)ws_size;
  const float* ip    = (const float*)d_in[0];
  const float* Wemb  = (const float*)d_in[1];
  const float* bemb  = (const float*)d_in[2];
  const float* dinit = (const float*)d_in[3];
  const float* Wi    = (const float*)d_in[4];
  const float* Wh    = (const float*)d_in[5];
  const float* bl    = (const float*)d_in[6];
  const float* Wqg   = (const float*)d_in[7];
  const float* Wrg   = (const float*)d_in[8];
  const float* vg    = (const float*)d_in[9];
  const float* Wqp   = (const float*)d_in[10];
  const float* Wrp   = (const float*)d_in[11];
  const float* vp    = (const float*)d_in[12];
  // d_in[13..16], d_in[18] dead: critic N=1 softmax == 1 => hy = e_c
  const float* Wrc   = (const float*)d_in[17];
  const float* W1    = (const float*)d_in[19];
  const float* b1    = (const float*)d_in[20];
  const float* W2    = (const float*)d_in[21];
  const float* b2    = (const float*)d_in[22];
  float* out = (float*)d_out;
  float* ws  = (float*)d_ws;

  k_pre<<<1, 512, 0, stream>>>(Wemb, bemb, dinit, Wi, bl, Wqp, Wrg, Wrp,
                               vg, vp, Wrc, W1, b1, W2, ws);
  k_mega<<<256, 512, 0, stream>>>(ip, Wh, Wqg, b2, ws, out);
}

// Round 6
// 727.220 us; speedup vs baseline: 4.1096x; 1.2468x over previous
//
#include <hip/hip_runtime.h>
#include <math.h>

#define Bsz 1024
#define Npt 50
#define Hd 128
#define G4 512
#define Tt 50
#define NEGC 1000000000.0f
#define CTANH 10.0f

#define OFF_R 0
#define OFF_V 1024
#define OFF_LP 2048
#define OFF_A 2562048
#define OFF_C 2613248
#define OFF_P 2715648

// ws float offsets (all tables; no bulk state)
#define WS_TG 0        // 128 float4 {Mg0, Mg1, vg, cg}
#define WS_TP 512      // 128 float4 {Mp0, Mp1, vp, cp}
#define WS_TQ 1024     // 128 float4 {Pg0, Pg1, cg@Wqp+cp, 0}
#define WS_A0 1536     // 512: We0@Wi
#define WS_A1 2048     // 512: We1@Wi
#define WS_A2 2560     // 512: bemb@Wi + bl
#define WS_A3 3072     // 512: dec_init@Wi + bl   (step 0)
#define WS_CT 3584     // 128 float4 {T0, T1, Tc(+b1), W2}

__device__ __forceinline__ float fsig(float x) {
  return __builtin_amdgcn_rcpf(1.0f + __expf(-x));
}

// branchless tanh: abs err ~2e-7 (rcp ulp), fine for score sums
__device__ __forceinline__ float ftanh(float x) {
  float e = __expf(2.0f * x);
  return 1.0f - 2.0f * __builtin_amdgcn_rcpf(e + 1.0f);
}

__device__ __forceinline__ float dpp_sum64(float x) {
  int v;
  v = __builtin_amdgcn_update_dpp(0, __float_as_int(x), 0x111, 0xf, 0xf, true);
  x += __int_as_float(v);
  v = __builtin_amdgcn_update_dpp(0, __float_as_int(x), 0x112, 0xf, 0xf, true);
  x += __int_as_float(v);
  v = __builtin_amdgcn_update_dpp(0, __float_as_int(x), 0x114, 0xf, 0xf, true);
  x += __int_as_float(v);
  v = __builtin_amdgcn_update_dpp(0, __float_as_int(x), 0x118, 0xf, 0xf, true);
  x += __int_as_float(v);
  v = __builtin_amdgcn_update_dpp(0, __float_as_int(x), 0x142, 0xf, 0xf, true);
  x += __int_as_float(v);
  v = __builtin_amdgcn_update_dpp(0, __float_as_int(x), 0x143, 0xf, 0xf, true);
  x += __int_as_float(v);
  return x;
}

__device__ __forceinline__ float xsum(float x) {
  #pragma unroll
  for (int off = 32; off >= 1; off >>= 1) x += __shfl_xor(x, off, 64);
  return x;
}
__device__ __forceinline__ float xmax(float x) {
  #pragma unroll
  for (int off = 32; off >= 1; off >>= 1) x = fmaxf(x, __shfl_xor(x, off, 64));
  return x;
}

// One block, 512 threads: all rank-2 tables + collapsed critic tables.
__global__ __launch_bounds__(512) void k_pre(const float* __restrict__ Wemb,
                                             const float* __restrict__ bemb,
                                             const float* __restrict__ dinit,
                                             const float* __restrict__ Wi,
                                             const float* __restrict__ bl,
                                             const float* __restrict__ Wqp,
                                             const float* __restrict__ Wrg,
                                             const float* __restrict__ Wrp,
                                             const float* __restrict__ vg,
                                             const float* __restrict__ vp,
                                             const float* __restrict__ Wrc,
                                             const float* __restrict__ W1,
                                             const float* __restrict__ b1,
                                             const float* __restrict__ W2,
                                             float* __restrict__ ws) {
  __shared__ float mg_s[2][128], mp_s[2][128], cg_s[128], cp_s[128];
  __shared__ float pg_s[2][128], pc_s[128];
  __shared__ float r0_s[128], r1_s[128], rc_s[128];
  int t = threadIdx.x;
  if (t < 256) {
    int j = t >> 7, hh = t & 127;
    float ag = 0.f, ap = 0.f;
    for (int k = 0; k < 128; ++k) {
      float we = Wemb[j * 128 + k];
      ag = fmaf(we, Wrg[k * 128 + hh], ag);
      ap = fmaf(we, Wrp[k * 128 + hh], ap);
    }
    mg_s[j][hh] = ag; mp_s[j][hh] = ap;
  } else if (t < 384) {
    int hh = t & 127;
    float cgv = 0.f, cpv = 0.f;
    for (int k = 0; k < 128; ++k) {
      float be = bemb[k];
      cgv = fmaf(be, Wrg[k * 128 + hh], cgv);
      cpv = fmaf(be, Wrp[k * 128 + hh], cpv);
    }
    cg_s[hh] = cgv; cp_s[hh] = cpv;
  } else {
    int hh = t & 127;
    float a0 = 0.f, a1 = 0.f, ac = 0.f;
    for (int k = 0; k < 128; ++k) {
      float wr = Wrc[k * 128 + hh];
      a0 = fmaf(Wemb[k], wr, a0);
      a1 = fmaf(Wemb[128 + k], wr, a1);
      ac = fmaf(bemb[k], wr, ac);
    }
    r0_s[hh] = a0; r1_s[hh] = a1; rc_s[hh] = ac;
  }
  __syncthreads();
  if (t < 256) {
    int j = t >> 7, hh = t & 127;
    float pg = 0.f;
    for (int k = 0; k < 128; ++k) pg = fmaf(mg_s[j][k], Wqp[k * 128 + hh], pg);
    pg_s[j][hh] = pg;
  } else if (t < 384) {
    int hh = t & 127;
    float pcv = 0.f;
    for (int k = 0; k < 128; ++k) pcv = fmaf(cg_s[k], Wqp[k * 128 + hh], pcv);
    pc_s[hh] = pcv + cp_s[hh];
  } else {
    int hh = t & 127;
    float t0 = 0.f, t1 = 0.f, tc = 0.f;
    for (int k = 0; k < 128; ++k) {
      float w1 = W1[k * 128 + hh];
      t0 = fmaf(r0_s[k], w1, t0);
      t1 = fmaf(r1_s[k], w1, t1);
      tc = fmaf(rc_s[k], w1, tc);
    }
    float4* w4 = (float4*)ws;
    w4[WS_CT / 4 + hh] = make_float4(t0, t1, tc + b1[hh], W2[hh]);
  }
  __syncthreads();
  if (t < 128) {
    float4* w4 = (float4*)ws;
    w4[WS_TG / 4 + t] = make_float4(mg_s[0][t], mg_s[1][t], vg[t], cg_s[t]);
    w4[WS_TP / 4 + t] = make_float4(mp_s[0][t], mp_s[1][t], vp[t], cp_s[t]);
    w4[WS_TQ / 4 + t] = make_float4(pg_s[0][t], pg_s[1][t], pc_s[t], 0.f);
  }
  {
    int j = t;
    float a0 = 0.f, a1 = 0.f, a2 = 0.f, a3 = 0.f;
    for (int k = 0; k < 128; ++k) {
      float wi = Wi[k * G4 + j];
      a0 = fmaf(Wemb[k], wi, a0);
      a1 = fmaf(Wemb[128 + k], wi, a1);
      a2 = fmaf(bemb[k], wi, a2);
      a3 = fmaf(dinit[k], wi, a3);
    }
    ws[WS_A0 + j] = a0;
    ws[WS_A1 + j] = a1;
    ws[WS_A2 + j] = a2 + bl[j];
    ws[WS_A3 + j] = a3 + bl[j];
  }
}

// Persistent: 256 blocks x 1024 threads (16 waves, 4/SIMD), 4 rows/block.
// Wh (64 f/thread) + Wqg (16 f/thread) register-resident; step loop has zero
// global reads. LDS ~108 KB -> 1 block/CU.
__global__ __launch_bounds__(1024, 4) void k_mega(const float* __restrict__ ip,
                                                  const float* __restrict__ Wh,
                                                  const float* __restrict__ Wqg,
                                                  const float* __restrict__ b2,
                                                  const float* __restrict__ ws,
                                                  float* __restrict__ out) {
  __shared__ __align__(16) float gpart[8][4][G4];     // 64 KB
  __shared__ __align__(16) float qpart[8][4][Hd];     // 16 KB
  __shared__ __align__(16) float h_s[4][Hd];
  __shared__ __align__(16) float c_s[4][Hd];
  __shared__ __align__(16) float qbuf[4][Hd];
  __shared__ __align__(16) float tg_s[G4];
  __shared__ __align__(16) float tp_s[G4];
  __shared__ __align__(16) float tq_s[G4];
  __shared__ __align__(16) float ct_s[G4];
  __shared__ __align__(16) float a0_s[G4], a1_s[G4], a2_s[G4], a3_s[G4];
  __shared__ __align__(16) float u_s[4][64];
  __shared__ __align__(16) float ip_s[4][Npt * 2];
  __shared__ float mask_s[4][Npt];
  __shared__ float ch_s[4][Npt * 2];
  __shared__ float sel_s[4][2];

  int t = threadIdx.x, blk = blockIdx.x;
  int w = t >> 6, lane = t & 63;
  int kh = t >> 7, jt = t & 127;     // 8 k-chunks x 128 cols

  // ---- register-resident weights ----
  float4 wv[16];                     // Wh[kh*16 .. +16)[jt*4 .. +4)
  #pragma unroll
  for (int j = 0; j < 16; ++j)
    wv[j] = *(const float4*)&Wh[(kh * 16 + j) * G4 + jt * 4];
  float wqr[16];                     // Wqg[kh*16 .. +16)[jt]
  #pragma unroll
  for (int j = 0; j < 16; ++j)
    wqr[j] = Wqg[(kh * 16 + j) * Hd + jt];

  // ---- stage tables + per-block state ----
  if (t < 128) {
    ((float4*)tg_s)[t] = ((const float4*)(ws + WS_TG))[t];
    ((float4*)tp_s)[t] = ((const float4*)(ws + WS_TP))[t];
    ((float4*)tq_s)[t] = ((const float4*)(ws + WS_TQ))[t];
    ((float4*)ct_s)[t] = ((const float4*)(ws + WS_CT))[t];
  } else if (t < 256) {
    int i = t - 128;
    ((float4*)a0_s)[i] = ((const float4*)(ws + WS_A0))[i];
    ((float4*)a1_s)[i] = ((const float4*)(ws + WS_A1))[i];
    ((float4*)a2_s)[i] = ((const float4*)(ws + WS_A2))[i];
    ((float4*)a3_s)[i] = ((const float4*)(ws + WS_A3))[i];
  }
  if (t < 200) {
    ((float2*)ip_s)[t] = ((const float2*)ip)[blk * 200 + t];
    ((float*)mask_s)[t] = 0.f;
  }
  if (t < 512) {
    int r = t >> 7, hh = t & 127;
    h_s[r][hh] = 0.f;
    c_s[r][hh] = 0.f;
  }
  if (t < 8) ((float*)sel_s)[t] = 0.f;
  __syncthreads();

  int cr = w & 3, ni = w >> 2;       // C/E: 4 waves per row, 13/13/13/11 n
  int nIter = (ni == 3) ? 11 : 13;

  for (int st = 0; st < Tt; ++st) {
    // ---- A1: h @ Wh partials from register weights ----
    {
      int k0 = kh * 16;
      #pragma unroll
      for (int r = 0; r < 4; ++r) {
        float4 ha = *(const float4*)&h_s[r][k0];
        float4 hb = *(const float4*)&h_s[r][k0 + 4];
        float4 hc = *(const float4*)&h_s[r][k0 + 8];
        float4 hd = *(const float4*)&h_s[r][k0 + 12];
        float hv[16] = {ha.x, ha.y, ha.z, ha.w, hb.x, hb.y, hb.z, hb.w,
                        hc.x, hc.y, hc.z, hc.w, hd.x, hd.y, hd.z, hd.w};
        float a0 = 0.f, a1 = 0.f, a2 = 0.f, a3 = 0.f;
        #pragma unroll
        for (int kk = 0; kk < 16; ++kk) {
          float4 wj = wv[kk];
          a0 = fmaf(hv[kk], wj.x, a0);
          a1 = fmaf(hv[kk], wj.y, a1);
          a2 = fmaf(hv[kk], wj.z, a2);
          a3 = fmaf(hv[kk], wj.w, a3);
        }
        *(float4*)&gpart[kh][r][jt * 4] = make_float4(a0, a1, a2, a3);
      }
    }
    __syncthreads();
    // ---- A2: combine + rank-2 x-part + LSTM cell ----
    if (t < 512) {
      int r = t >> 7, hh = t & 127;
      float p0 = sel_s[r][0], p1 = sel_s[r][1];
      float g[4];
      #pragma unroll
      for (int gi = 0; gi < 4; ++gi) {
        int j = gi * 128 + hh;
        float x = (st == 0) ? a3_s[j]
                            : fmaf(p0, a0_s[j], fmaf(p1, a1_s[j], a2_s[j]));
        #pragma unroll
        for (int k8 = 0; k8 < 8; ++k8) x += gpart[k8][r][j];
        g[gi] = x;
      }
      float c2 = fsig(g[1]) * c_s[r][hh] + fsig(g[0]) * ftanh(g[2]);
      float h2 = fsig(g[3]) * ftanh(c2);
      c_s[r][hh] = c2;
      h_s[r][hh] = h2;
    }
    __syncthreads();
    // ---- B: qpart = h2 @ Wqg (k-split 8-way, register weights) ----
    {
      int k0 = kh * 16;
      #pragma unroll
      for (int r = 0; r < 4; ++r) {
        float4 ha = *(const float4*)&h_s[r][k0];
        float4 hb = *(const float4*)&h_s[r][k0 + 4];
        float4 hc = *(const float4*)&h_s[r][k0 + 8];
        float4 hd = *(const float4*)&h_s[r][k0 + 12];
        float hv[16] = {ha.x, ha.y, ha.z, ha.w, hb.x, hb.y, hb.z, hb.w,
                        hc.x, hc.y, hc.z, hc.w, hd.x, hd.y, hd.z, hd.w};
        float a = 0.f;
        #pragma unroll
        for (int kk = 0; kk < 16; ++kk) a = fmaf(hv[kk], wqr[kk], a);
        qpart[kh][r][jt] = a;
      }
    }
    __syncthreads();
    // ---- C: glimpse scores u[n] = vg . tanh(eg(n) + q) ----
    {
      float4 tA = ((float4*)tg_s)[lane];
      float4 tB = ((float4*)tg_s)[64 + lane];
      float q0 = tA.w, q1 = tB.w;
      #pragma unroll
      for (int k8 = 0; k8 < 8; ++k8) {
        q0 += qpart[k8][cr][lane];
        q1 += qpart[k8][cr][64 + lane];
      }
      for (int i = 0; i < nIter; ++i) {
        int n = ni * 13 + i;
        float2 pn = ((float2*)ip_s)[cr * Npt + n];
        float a0 = fmaf(pn.x, tA.x, fmaf(pn.y, tA.y, q0));
        float a1 = fmaf(pn.x, tB.x, fmaf(pn.y, tB.y, q1));
        float s = tA.z * ftanh(a0) + tB.z * ftanh(a1);
        s = dpp_sum64(s);
        if (lane == 63) u_s[cr][n] = s;
      }
    }
    __syncthreads();
    // ---- D: glimpse softmax -> (s0,s1) -> rank-2 pointer query ----
    if (w < 4) {
      int r = w;
      float2 ipn = make_float2(0.f, 0.f);
      float x = -INFINITY;
      if (lane < Npt) {
        ipn = ((float2*)ip_s)[r * Npt + lane];
        x = u_s[r][lane] - NEGC * mask_s[r][lane];
      }
      float m = xmax(x);
      float e = (lane < Npt) ? __expf(x - m) : 0.f;
      float ssum = xsum(e);
      float p = e / ssum;
      float s0 = xsum(p * ipn.x);
      float s1 = xsum(p * ipn.y);
      float4 tq0 = ((float4*)tq_s)[lane];
      float4 tq1 = ((float4*)tq_s)[64 + lane];
      qbuf[r][lane]      = fmaf(s0, tq0.x, fmaf(s1, tq0.y, tq0.z));
      qbuf[r][64 + lane] = fmaf(s0, tq1.x, fmaf(s1, tq1.y, tq1.z));
    }
    __syncthreads();
    // ---- E: pointer scores (raw; CTANH*tanh applied in F) ----
    {
      float4 tA = ((float4*)tp_s)[lane];
      float4 tB = ((float4*)tp_s)[64 + lane];
      float q0 = qbuf[cr][lane], q1 = qbuf[cr][64 + lane];
      for (int i = 0; i < nIter; ++i) {
        int n = ni * 13 + i;
        float2 pn = ((float2*)ip_s)[cr * Npt + n];
        float a0 = fmaf(pn.x, tA.x, fmaf(pn.y, tA.y, q0));
        float a1 = fmaf(pn.x, tB.x, fmaf(pn.y, tB.y, q1));
        float s = tA.z * ftanh(a0) + tB.z * ftanh(a1);
        s = dpp_sum64(s);
        if (lane == 63) u_s[cr][n] = s;
      }
    }
    __syncthreads();
    // ---- F: logit = C*tanh(u) - NEG*mask; softmax/argmax/outputs ----
    if (w < 4) {
      int r = w, b = blk * 4 + r;
      float2 ipn = make_float2(0.f, 0.f);
      float x = -INFINITY;
      if (lane < Npt) {
        ipn = ((float2*)ip_s)[r * Npt + lane];
        x = CTANH * ftanh(u_s[r][lane]) - NEGC * mask_s[r][lane];
      }
      float m = xmax(x);
      float sh = x - m;
      float e = (lane < Npt) ? __expf(sh) : 0.f;
      float ssum = xsum(e);
      float ls = __logf(ssum);
      float prob = e / ssum;
      if (lane < Npt) {
        out[OFF_LP + ((size_t)b * Tt + st) * Npt + lane] = sh - ls;
        out[OFF_P + ((size_t)b * Tt + st) * Npt + lane] = prob;
      }
      float pv = (lane < Npt) ? prob : -1.f;
      int idx = lane;
      #pragma unroll
      for (int off = 32; off >= 1; off >>= 1) {
        float po = __shfl_xor(pv, off, 64);
        int io = __shfl_xor(idx, off, 64);
        if (po > pv || (po == pv && io < idx)) { pv = po; idx = io; }
      }
      int a = idx;
      float p0a = __shfl(ipn.x, a, 64);
      float p1a = __shfl(ipn.y, a, 64);
      if (lane == 0) {
        out[OFF_A + (size_t)b * Tt + st] = (float)a;
        out[OFF_C + ((size_t)b * Tt + st) * 2 + 0] = p0a;
        out[OFF_C + ((size_t)b * Tt + st) * 2 + 1] = p1a;
        ((float2*)ch_s)[r * Npt + st] = make_float2(p0a, p1a);
        mask_s[r][a] = 1.0f;
        sel_s[r][0] = p0a;
        sel_s[r][1] = p1a;
      }
    }
    __syncthreads();
  }

  // ---- epilogue: collapsed critic + tour length ----
  if (w < 4) {
    int r = w, b = blk * 4 + r;
    float p0 = sel_s[r][0], p1 = sel_s[r][1];
    float4 ct0 = ((float4*)ct_s)[lane];
    float4 ct1 = ((float4*)ct_s)[64 + lane];
    float t1a = fmaxf(fmaf(p0, ct0.x, fmaf(p1, ct0.y, ct0.z)), 0.f);
    float t1b = fmaxf(fmaf(p0, ct1.x, fmaf(p1, ct1.y, ct1.z)), 0.f);
    float sv = xsum(t1a * ct0.w + t1b * ct1.w);
    if (lane == 0) out[OFF_V + b] = sv + b2[0];
    float rr = 0.f;
    if (lane < Npt) {
      float2 c0 = ((float2*)ch_s)[r * Npt + lane];
      float2 c1 = ((float2*)ch_s)[r * Npt + ((lane == Npt - 1) ? 0 : lane + 1)];
      float dx = c1.x - c0.x, dy = c1.y - c0.y;
      rr = sqrtf(dx * dx + dy * dy + 1e-10f);
    }
    rr = xsum(rr);
    if (lane == 0) out[OFF_R + b] = rr;
  }
}

extern "C" void kernel_launch(void* const* d_in, const int* in_sizes, int n_in,
                              void* d_out, int out_size, void* d_ws, size_t ws_size,
                              hipStream_t stream) {
  (void)in_sizes; (void)n_in; (void)out_size; (void)ws_size;
  const float* ip    = (const float*)d_in[0];
  const float* Wemb  = (const float*)d_in[1];
  const float* bemb  = (const float*)d_in[2];
  const float* dinit = (const float*)d_in[3];
  const float* Wi    = (const float*)d_in[4];
  const float* Wh    = (const float*)d_in[5];
  const float* bl    = (const float*)d_in[6];
  const float* Wqg   = (const float*)d_in[7];
  const float* Wrg   = (const float*)d_in[8];
  const float* vg    = (const float*)d_in[9];
  const float* Wqp   = (const float*)d_in[10];
  const float* Wrp   = (const float*)d_in[11];
  const float* vp    = (const float*)d_in[12];
  // d_in[13..16], d_in[18] dead: critic N=1 softmax == 1 => hy = e_c
  const float* Wrc   = (const float*)d_in[17];
  const float* W1    = (const float*)d_in[19];
  const float* b1    = (const float*)d_in[20];
  const float* W2    = (const float*)d_in[21];
  const float* b2    = (const float*)d_in[22];
  float* out = (float*)d_out;
  float* ws  = (float*)d_ws;

  k_pre<<<1, 512, 0, stream>>>(Wemb, bemb, dinit, Wi, bl, Wqp, Wrg, Wrp,
                               vg, vp, Wrc, W1, b1, W2, ws);
  k_mega<<<256, 1024, 0, stream>>>(ip, Wh, Wqg, b2, ws, out);
}

// Round 7
// 715.054 us; speedup vs baseline: 4.1796x; 1.0170x over previous
//
#include <hip/hip_runtime.h>
#include <math.h>

#define Bsz 1024
#define Npt 50
#define Hd 128
#define G4 512
#define Tt 50
#define NEGC 1000000000.0f
#define CTANH 10.0f

#define OFF_R 0
#define OFF_V 1024
#define OFF_LP 2048
#define OFF_A 2562048
#define OFF_C 2613248
#define OFF_P 2715648

// ws float offsets (all tables; no bulk state)
#define WS_TG 0        // 128 float4 {Mg0, Mg1, vg, cg}
#define WS_TP 512      // 128 float4 {Mp0, Mp1, vp, cp}
#define WS_TQ 1024     // 128 float4 {Pg0, Pg1, cg@Wqp+cp, 0}
#define WS_A0 1536     // 512: We0@Wi
#define WS_A1 2048     // 512: We1@Wi
#define WS_A2 2560     // 512: bemb@Wi + bl
#define WS_A3 3072     // 512: dec_init@Wi + bl   (step 0)
#define WS_CT 3584     // 128 float4 {T0, T1, Tc(+b1), W2}

__device__ __forceinline__ float fsig(float x) {
  return __builtin_amdgcn_rcpf(1.0f + __expf(-x));
}

// branchless tanh: abs err ~2e-7 (rcp ulp), fine for score sums
__device__ __forceinline__ float ftanh(float x) {
  float e = __expf(2.0f * x);
  return 1.0f - 2.0f * __builtin_amdgcn_rcpf(e + 1.0f);
}

__device__ __forceinline__ float xsum(float x) {
  #pragma unroll
  for (int off = 32; off >= 1; off >>= 1) x += __shfl_xor(x, off, 64);
  return x;
}
__device__ __forceinline__ float xmax(float x) {
  #pragma unroll
  for (int off = 32; off >= 1; off >>= 1) x = fmaxf(x, __shfl_xor(x, off, 64));
  return x;
}

// One block, 512 threads: all rank-2 tables + collapsed critic tables.
__global__ __launch_bounds__(512) void k_pre(const float* __restrict__ Wemb,
                                             const float* __restrict__ bemb,
                                             const float* __restrict__ dinit,
                                             const float* __restrict__ Wi,
                                             const float* __restrict__ bl,
                                             const float* __restrict__ Wqp,
                                             const float* __restrict__ Wrg,
                                             const float* __restrict__ Wrp,
                                             const float* __restrict__ vg,
                                             const float* __restrict__ vp,
                                             const float* __restrict__ Wrc,
                                             const float* __restrict__ W1,
                                             const float* __restrict__ b1,
                                             const float* __restrict__ W2,
                                             float* __restrict__ ws) {
  __shared__ float mg_s[2][128], mp_s[2][128], cg_s[128], cp_s[128];
  __shared__ float pg_s[2][128], pc_s[128];
  __shared__ float r0_s[128], r1_s[128], rc_s[128];
  int t = threadIdx.x;
  if (t < 256) {
    int j = t >> 7, hh = t & 127;
    float ag = 0.f, ap = 0.f;
    for (int k = 0; k < 128; ++k) {
      float we = Wemb[j * 128 + k];
      ag = fmaf(we, Wrg[k * 128 + hh], ag);
      ap = fmaf(we, Wrp[k * 128 + hh], ap);
    }
    mg_s[j][hh] = ag; mp_s[j][hh] = ap;
  } else if (t < 384) {
    int hh = t & 127;
    float cgv = 0.f, cpv = 0.f;
    for (int k = 0; k < 128; ++k) {
      float be = bemb[k];
      cgv = fmaf(be, Wrg[k * 128 + hh], cgv);
      cpv = fmaf(be, Wrp[k * 128 + hh], cpv);
    }
    cg_s[hh] = cgv; cp_s[hh] = cpv;
  } else {
    int hh = t & 127;
    float a0 = 0.f, a1 = 0.f, ac = 0.f;
    for (int k = 0; k < 128; ++k) {
      float wr = Wrc[k * 128 + hh];
      a0 = fmaf(Wemb[k], wr, a0);
      a1 = fmaf(Wemb[128 + k], wr, a1);
      ac = fmaf(bemb[k], wr, ac);
    }
    r0_s[hh] = a0; r1_s[hh] = a1; rc_s[hh] = ac;
  }
  __syncthreads();
  if (t < 256) {
    int j = t >> 7, hh = t & 127;
    float pg = 0.f;
    for (int k = 0; k < 128; ++k) pg = fmaf(mg_s[j][k], Wqp[k * 128 + hh], pg);
    pg_s[j][hh] = pg;
  } else if (t < 384) {
    int hh = t & 127;
    float pcv = 0.f;
    for (int k = 0; k < 128; ++k) pcv = fmaf(cg_s[k], Wqp[k * 128 + hh], pcv);
    pc_s[hh] = pcv + cp_s[hh];
  } else {
    int hh = t & 127;
    float t0 = 0.f, t1 = 0.f, tc = 0.f;
    for (int k = 0; k < 128; ++k) {
      float w1 = W1[k * 128 + hh];
      t0 = fmaf(r0_s[k], w1, t0);
      t1 = fmaf(r1_s[k], w1, t1);
      tc = fmaf(rc_s[k], w1, tc);
    }
    float4* w4 = (float4*)ws;
    w4[WS_CT / 4 + hh] = make_float4(t0, t1, tc + b1[hh], W2[hh]);
  }
  __syncthreads();
  if (t < 128) {
    float4* w4 = (float4*)ws;
    w4[WS_TG / 4 + t] = make_float4(mg_s[0][t], mg_s[1][t], vg[t], cg_s[t]);
    w4[WS_TP / 4 + t] = make_float4(mp_s[0][t], mp_s[1][t], vp[t], cp_s[t]);
    w4[WS_TQ / 4 + t] = make_float4(pg_s[0][t], pg_s[1][t], pc_s[t], 0.f);
  }
  {
    int j = t;
    float a0 = 0.f, a1 = 0.f, a2 = 0.f, a3 = 0.f;
    for (int k = 0; k < 128; ++k) {
      float wi = Wi[k * G4 + j];
      a0 = fmaf(Wemb[k], wi, a0);
      a1 = fmaf(Wemb[128 + k], wi, a1);
      a2 = fmaf(bemb[k], wi, a2);
      a3 = fmaf(dinit[k], wi, a3);
    }
    ws[WS_A0 + j] = a0;
    ws[WS_A1 + j] = a1;
    ws[WS_A2 + j] = a2 + bl[j];
    ws[WS_A3 + j] = a3 + bl[j];
  }
}

// Persistent: 256 blocks x 1024 threads (16 waves, 4/SIMD), 4 rows/block.
// Wh (64 f/thread) + Wqg (16 f/thread) register-resident; step loop has zero
// global reads. Score phases: n-per-lane over 32-h chunks (no cross-lane
// reductions in C/E); D/F combine 4 partials + softmax/argmax per row.
__global__ __launch_bounds__(1024, 4) void k_mega(const float* __restrict__ ip,
                                                  const float* __restrict__ Wh,
                                                  const float* __restrict__ Wqg,
                                                  const float* __restrict__ b2,
                                                  const float* __restrict__ ws,
                                                  float* __restrict__ out) {
  __shared__ __align__(16) float gpart[8][4][G4];     // 64 KB
  __shared__ __align__(16) float qpart[8][4][Hd];     // 16 KB
  __shared__ __align__(16) float q_w[16][32];         // per-wave q chunk
  __shared__ __align__(16) float up_s[4][4][64];      // partial u: [j][row][n]
  __shared__ __align__(16) float h_s[4][Hd];
  __shared__ __align__(16) float c_s[4][Hd];
  __shared__ __align__(16) float qbuf[4][Hd];
  __shared__ __align__(16) float tg_s[G4];
  __shared__ __align__(16) float tp_s[G4];
  __shared__ __align__(16) float tq_s[G4];
  __shared__ __align__(16) float ct_s[G4];
  __shared__ __align__(16) float a0_s[G4], a1_s[G4], a2_s[G4], a3_s[G4];
  __shared__ __align__(16) float ip_s[4][Npt * 2];
  __shared__ float mask_s[4][Npt];
  __shared__ float ch_s[4][Npt * 2];
  __shared__ float sel_s[4][2];

  int t = threadIdx.x, blk = blockIdx.x;
  int w = t >> 6, lane = t & 63;
  int kh = t >> 7, jt = t & 127;     // 8 k-chunks x 128 cols

  // ---- register-resident weights ----
  float4 wv[16];                     // Wh[kh*16 .. +16)[jt*4 .. +4)
  #pragma unroll
  for (int j = 0; j < 16; ++j)
    wv[j] = *(const float4*)&Wh[(kh * 16 + j) * G4 + jt * 4];
  float wqr[16];                     // Wqg[kh*16 .. +16)[jt]
  #pragma unroll
  for (int j = 0; j < 16; ++j)
    wqr[j] = Wqg[(kh * 16 + j) * Hd + jt];

  // ---- stage tables + per-block state ----
  if (t < 128) {
    ((float4*)tg_s)[t] = ((const float4*)(ws + WS_TG))[t];
    ((float4*)tp_s)[t] = ((const float4*)(ws + WS_TP))[t];
    ((float4*)tq_s)[t] = ((const float4*)(ws + WS_TQ))[t];
    ((float4*)ct_s)[t] = ((const float4*)(ws + WS_CT))[t];
  } else if (t < 256) {
    int i = t - 128;
    ((float4*)a0_s)[i] = ((const float4*)(ws + WS_A0))[i];
    ((float4*)a1_s)[i] = ((const float4*)(ws + WS_A1))[i];
    ((float4*)a2_s)[i] = ((const float4*)(ws + WS_A2))[i];
    ((float4*)a3_s)[i] = ((const float4*)(ws + WS_A3))[i];
  }
  if (t < 200) {
    ((float2*)ip_s)[t] = ((const float2*)ip)[blk * 200 + t];
    ((float*)mask_s)[t] = 0.f;
  }
  if (t < 512) {
    int r = t >> 7, hh = t & 127;
    h_s[r][hh] = 0.f;
    c_s[r][hh] = 0.f;
  }
  if (t < 8) ((float*)sel_s)[t] = 0.f;
  __syncthreads();

  int cr = w & 3, cj = w >> 2;       // C/E: wave (row, h-chunk), n per lane

  for (int st = 0; st < Tt; ++st) {
    // ---- A1: h @ Wh partials from register weights ----
    {
      int k0 = kh * 16;
      #pragma unroll
      for (int r = 0; r < 4; ++r) {
        float4 ha = *(const float4*)&h_s[r][k0];
        float4 hb = *(const float4*)&h_s[r][k0 + 4];
        float4 hc = *(const float4*)&h_s[r][k0 + 8];
        float4 hd = *(const float4*)&h_s[r][k0 + 12];
        float hv[16] = {ha.x, ha.y, ha.z, ha.w, hb.x, hb.y, hb.z, hb.w,
                        hc.x, hc.y, hc.z, hc.w, hd.x, hd.y, hd.z, hd.w};
        float a0 = 0.f, a1 = 0.f, a2 = 0.f, a3 = 0.f;
        #pragma unroll
        for (int kk = 0; kk < 16; ++kk) {
          float4 wj = wv[kk];
          a0 = fmaf(hv[kk], wj.x, a0);
          a1 = fmaf(hv[kk], wj.y, a1);
          a2 = fmaf(hv[kk], wj.z, a2);
          a3 = fmaf(hv[kk], wj.w, a3);
        }
        *(float4*)&gpart[kh][r][jt * 4] = make_float4(a0, a1, a2, a3);
      }
    }
    __syncthreads();
    // ---- A2: combine + rank-2 x-part + LSTM cell ----
    if (t < 512) {
      int r = t >> 7, hh = t & 127;
      float p0 = sel_s[r][0], p1 = sel_s[r][1];
      float g[4];
      #pragma unroll
      for (int gi = 0; gi < 4; ++gi) {
        int j = gi * 128 + hh;
        float x = (st == 0) ? a3_s[j]
                            : fmaf(p0, a0_s[j], fmaf(p1, a1_s[j], a2_s[j]));
        #pragma unroll
        for (int k8 = 0; k8 < 8; ++k8) x += gpart[k8][r][j];
        g[gi] = x;
      }
      float c2 = fsig(g[1]) * c_s[r][hh] + fsig(g[0]) * ftanh(g[2]);
      float h2 = fsig(g[3]) * ftanh(c2);
      c_s[r][hh] = c2;
      h_s[r][hh] = h2;
    }
    __syncthreads();
    // ---- B: qpart = h2 @ Wqg (k-split 8-way, register weights) ----
    {
      int k0 = kh * 16;
      #pragma unroll
      for (int r = 0; r < 4; ++r) {
        float4 ha = *(const float4*)&h_s[r][k0];
        float4 hb = *(const float4*)&h_s[r][k0 + 4];
        float4 hc = *(const float4*)&h_s[r][k0 + 8];
        float4 hd = *(const float4*)&h_s[r][k0 + 12];
        float hv[16] = {ha.x, ha.y, ha.z, ha.w, hb.x, hb.y, hb.z, hb.w,
                        hc.x, hc.y, hc.z, hc.w, hd.x, hd.y, hd.z, hd.w};
        float a = 0.f;
        #pragma unroll
        for (int kk = 0; kk < 16; ++kk) a = fmaf(hv[kk], wqr[kk], a);
        qpart[kh][r][jt] = a;
      }
    }
    __syncthreads();
    // ---- C: glimpse partial scores, n per lane over 32-h chunk ----
    {
      if (lane < 32) {
        int h = cj * 32 + lane;
        float qs = ((float4*)tg_s)[h].w;   // cg
        #pragma unroll
        for (int k = 0; k < 8; ++k) qs += qpart[k][cr][h];
        q_w[w][lane] = qs;
      }
      float2 pn = make_float2(0.f, 0.f);
      if (lane < Npt) pn = ((float2*)ip_s)[cr * Npt + lane];
      float acc = 0.f;
      #pragma unroll 8
      for (int hp = 0; hp < 32; ++hp) {
        float4 tg4 = ((float4*)tg_s)[cj * 32 + hp];
        float a = fmaf(pn.x, tg4.x, fmaf(pn.y, tg4.y, q_w[w][hp]));
        acc = fmaf(tg4.z, ftanh(a), acc);
      }
      up_s[cj][cr][lane] = acc;
    }
    __syncthreads();
    // ---- D: glimpse softmax -> (s0,s1) -> rank-2 pointer query ----
    if (w < 4) {
      int r = w;
      float2 ipn = make_float2(0.f, 0.f);
      float x = -INFINITY;
      if (lane < Npt) {
        ipn = ((float2*)ip_s)[r * Npt + lane];
        float u = up_s[0][r][lane] + up_s[1][r][lane]
                + up_s[2][r][lane] + up_s[3][r][lane];
        x = u - NEGC * mask_s[r][lane];
      }
      float m = xmax(x);
      float e = (lane < Npt) ? __expf(x - m) : 0.f;
      float ssum = xsum(e);
      float p = e / ssum;
      float s0 = xsum(p * ipn.x);
      float s1 = xsum(p * ipn.y);
      float4 tq0 = ((float4*)tq_s)[lane];
      float4 tq1 = ((float4*)tq_s)[64 + lane];
      qbuf[r][lane]      = fmaf(s0, tq0.x, fmaf(s1, tq0.y, tq0.z));
      qbuf[r][64 + lane] = fmaf(s0, tq1.x, fmaf(s1, tq1.y, tq1.z));
    }
    __syncthreads();
    // ---- E: pointer partial scores, n per lane over 32-h chunk ----
    {
      float2 pn = make_float2(0.f, 0.f);
      if (lane < Npt) pn = ((float2*)ip_s)[cr * Npt + lane];
      float acc = 0.f;
      #pragma unroll 8
      for (int hp = 0; hp < 32; ++hp) {
        int h = cj * 32 + hp;
        float4 tp4 = ((float4*)tp_s)[h];
        float a = fmaf(pn.x, tp4.x, fmaf(pn.y, tp4.y, qbuf[cr][h]));
        acc = fmaf(tp4.z, ftanh(a), acc);
      }
      up_s[cj][cr][lane] = acc;
    }
    __syncthreads();
    // ---- F: logit = C*tanh(u) - NEG*mask; softmax/argmax/outputs ----
    if (w < 4) {
      int r = w, b = blk * 4 + r;
      float x = -INFINITY;
      if (lane < Npt) {
        float u = up_s[0][r][lane] + up_s[1][r][lane]
                + up_s[2][r][lane] + up_s[3][r][lane];
        x = CTANH * ftanh(u) - NEGC * mask_s[r][lane];
      }
      float m = xmax(x);
      float sh = x - m;
      float e = (lane < Npt) ? __expf(sh) : 0.f;
      float ssum = xsum(e);
      float ls = __logf(ssum);
      float prob = e / ssum;
      if (lane < Npt) {
        out[OFF_LP + ((size_t)b * Tt + st) * Npt + lane] = sh - ls;
        out[OFF_P + ((size_t)b * Tt + st) * Npt + lane] = prob;
      }
      float pv = (lane < Npt) ? prob : -1.f;
      float mx = xmax(pv);
      unsigned long long bal = __ballot(pv == mx);
      int a = __ffsll(bal) - 1;      // first max index (np.argmax tie-break)
      float p0a = ip_s[r][2 * a];    // broadcast LDS reads
      float p1a = ip_s[r][2 * a + 1];
      if (lane == 0) {
        out[OFF_A + (size_t)b * Tt + st] = (float)a;
        out[OFF_C + ((size_t)b * Tt + st) * 2 + 0] = p0a;
        out[OFF_C + ((size_t)b * Tt + st) * 2 + 1] = p1a;
        ((float2*)ch_s)[r * Npt + st] = make_float2(p0a, p1a);
        mask_s[r][a] = 1.0f;
        sel_s[r][0] = p0a;
        sel_s[r][1] = p1a;
      }
    }
    __syncthreads();
  }

  // ---- epilogue: collapsed critic + tour length ----
  if (w < 4) {
    int r = w, b = blk * 4 + r;
    float p0 = sel_s[r][0], p1 = sel_s[r][1];
    float4 ct0 = ((float4*)ct_s)[lane];
    float4 ct1 = ((float4*)ct_s)[64 + lane];
    float t1a = fmaxf(fmaf(p0, ct0.x, fmaf(p1, ct0.y, ct0.z)), 0.f);
    float t1b = fmaxf(fmaf(p0, ct1.x, fmaf(p1, ct1.y, ct1.z)), 0.f);
    float sv = xsum(t1a * ct0.w + t1b * ct1.w);
    if (lane == 0) out[OFF_V + b] = sv + b2[0];
    float rr = 0.f;
    if (lane < Npt) {
      float2 c0 = ((float2*)ch_s)[r * Npt + lane];
      float2 c1 = ((float2*)ch_s)[r * Npt + ((lane == Npt - 1) ? 0 : lane + 1)];
      float dx = c1.x - c0.x, dy = c1.y - c0.y;
      rr = sqrtf(dx * dx + dy * dy + 1e-10f);
    }
    rr = xsum(rr);
    if (lane == 0) out[OFF_R + b] = rr;
  }
}

extern "C" void kernel_launch(void* const* d_in, const int* in_sizes, int n_in,
                              void* d_out, int out_size, void* d_ws, size_t ws_size,
                              hipStream_t stream) {
  (void)in_sizes; (void)n_in; (void)out_size; (void)ws_size;
  const float* ip    = (const float*)d_in[0];
  const float* Wemb  = (const float*)d_in[1];
  const float* bemb  = (const float*)d_in[2];
  const float* dinit = (const float*)d_in[3];
  const float* Wi    = (const float*)d_in[4];
  const float* Wh    = (const float*)d_in[5];
  const float* bl    = (const float*)d_in[6];
  const float* Wqg   = (const float*)d_in[7];
  const float* Wrg   = (const float*)d_in[8];
  const float* vg    = (const float*)d_in[9];
  const float* Wqp   = (const float*)d_in[10];
  const float* Wrp   = (const float*)d_in[11];
  const float* vp    = (const float*)d_in[12];
  // d_in[13..16], d_in[18] dead: critic N=1 softmax == 1 => hy = e_c
  const float* Wrc   = (const float*)d_in[17];
  const float* W1    = (const float*)d_in[19];
  const float* b1    = (const float*)d_in[20];
  const float* W2    = (const float*)d_in[21];
  const float* b2    = (const float*)d_in[22];
  float* out = (float*)d_out;
  float* ws  = (float*)d_ws;

  k_pre<<<1, 512, 0, stream>>>(Wemb, bemb, dinit, Wi, bl, Wqp, Wrg, Wrp,
                               vg, vp, Wrc, W1, b1, W2, ws);
  k_mega<<<256, 1024, 0, stream>>>(ip, Wh, Wqg, b2, ws, out);
}

// Round 8
// 677.666 us; speedup vs baseline: 4.4102x; 1.0552x over previous
//
#include <hip/hip_runtime.h>
#include <math.h>

#define Bsz 1024
#define Npt 50
#define Hd 128
#define G4 512
#define Tt 50
#define NEGC 1000000000.0f
#define CTANH 10.0f

#define OFF_R 0
#define OFF_V 1024
#define OFF_LP 2048
#define OFF_A 2562048
#define OFF_C 2613248
#define OFF_P 2715648

// ws float offsets (all tables; no bulk state)
#define WS_TG 0        // 128 float4 {Mg0, Mg1, vg, cg}
#define WS_TP 512      // 128 float4 {Mp0, Mp1, vp, cp}
#define WS_TQ 1024     // 128 float4 {Pg0, Pg1, cg@Wqp+cp, 0}
#define WS_A0 1536     // 512: We0@Wi
#define WS_A1 2048     // 512: We1@Wi
#define WS_A2 2560     // 512: bemb@Wi + bl
#define WS_A3 3072     // 512: dec_init@Wi + bl   (step 0)
#define WS_CT 3584     // 128 float4 {T0, T1, Tc(+b1), W2}

__device__ __forceinline__ float fsig(float x) {
  return __builtin_amdgcn_rcpf(1.0f + __expf(-x));
}

// branchless tanh: abs err ~2e-7 (rcp ulp)
__device__ __forceinline__ float ftanh(float x) {
  float e = __expf(2.0f * x);
  return 1.0f - 2.0f * __builtin_amdgcn_rcpf(e + 1.0f);
}

// wave64 sum via DPP row_shr cascade + row_bcast; broadcast via readlane(63)
__device__ __forceinline__ float dpp_sum_bcast(float x) {
  int v;
  v = __builtin_amdgcn_update_dpp(0, __float_as_int(x), 0x111, 0xf, 0xf, true);
  x += __int_as_float(v);
  v = __builtin_amdgcn_update_dpp(0, __float_as_int(x), 0x112, 0xf, 0xf, true);
  x += __int_as_float(v);
  v = __builtin_amdgcn_update_dpp(0, __float_as_int(x), 0x114, 0xf, 0xf, true);
  x += __int_as_float(v);
  v = __builtin_amdgcn_update_dpp(0, __float_as_int(x), 0x118, 0xf, 0xf, true);
  x += __int_as_float(v);
  v = __builtin_amdgcn_update_dpp(0, __float_as_int(x), 0x142, 0xf, 0xf, true);
  x += __int_as_float(v);
  v = __builtin_amdgcn_update_dpp(0, __float_as_int(x), 0x143, 0xf, 0xf, true);
  x += __int_as_float(v);
  return __int_as_float(__builtin_amdgcn_readlane(__float_as_int(x), 63));
}

// wave64 max via DPP; REQUIRES x >= 0 (bound_ctrl zero-fill enters fmax)
__device__ __forceinline__ float dpp_max_bcast(float x) {
  int v;
  v = __builtin_amdgcn_update_dpp(0, __float_as_int(x), 0x111, 0xf, 0xf, true);
  x = fmaxf(x, __int_as_float(v));
  v = __builtin_amdgcn_update_dpp(0, __float_as_int(x), 0x112, 0xf, 0xf, true);
  x = fmaxf(x, __int_as_float(v));
  v = __builtin_amdgcn_update_dpp(0, __float_as_int(x), 0x114, 0xf, 0xf, true);
  x = fmaxf(x, __int_as_float(v));
  v = __builtin_amdgcn_update_dpp(0, __float_as_int(x), 0x118, 0xf, 0xf, true);
  x = fmaxf(x, __int_as_float(v));
  v = __builtin_amdgcn_update_dpp(0, __float_as_int(x), 0x142, 0xf, 0xf, true);
  x = fmaxf(x, __int_as_float(v));
  v = __builtin_amdgcn_update_dpp(0, __float_as_int(x), 0x143, 0xf, 0xf, true);
  x = fmaxf(x, __int_as_float(v));
  return __int_as_float(__builtin_amdgcn_readlane(__float_as_int(x), 63));
}

__device__ __forceinline__ float xsum(float x) {
  #pragma unroll
  for (int off = 32; off >= 1; off >>= 1) x += __shfl_xor(x, off, 64);
  return x;
}

// One block, 512 threads: all rank-2 tables + collapsed critic tables.
__global__ __launch_bounds__(512) void k_pre(const float* __restrict__ Wemb,
                                             const float* __restrict__ bemb,
                                             const float* __restrict__ dinit,
                                             const float* __restrict__ Wi,
                                             const float* __restrict__ bl,
                                             const float* __restrict__ Wqp,
                                             const float* __restrict__ Wrg,
                                             const float* __restrict__ Wrp,
                                             const float* __restrict__ vg,
                                             const float* __restrict__ vp,
                                             const float* __restrict__ Wrc,
                                             const float* __restrict__ W1,
                                             const float* __restrict__ b1,
                                             const float* __restrict__ W2,
                                             float* __restrict__ ws) {
  __shared__ float mg_s[2][128], mp_s[2][128], cg_s[128], cp_s[128];
  __shared__ float pg_s[2][128], pc_s[128];
  __shared__ float r0_s[128], r1_s[128], rc_s[128];
  int t = threadIdx.x;
  if (t < 256) {
    int j = t >> 7, hh = t & 127;
    float ag = 0.f, ap = 0.f;
    for (int k = 0; k < 128; ++k) {
      float we = Wemb[j * 128 + k];
      ag = fmaf(we, Wrg[k * 128 + hh], ag);
      ap = fmaf(we, Wrp[k * 128 + hh], ap);
    }
    mg_s[j][hh] = ag; mp_s[j][hh] = ap;
  } else if (t < 384) {
    int hh = t & 127;
    float cgv = 0.f, cpv = 0.f;
    for (int k = 0; k < 128; ++k) {
      float be = bemb[k];
      cgv = fmaf(be, Wrg[k * 128 + hh], cgv);
      cpv = fmaf(be, Wrp[k * 128 + hh], cpv);
    }
    cg_s[hh] = cgv; cp_s[hh] = cpv;
  } else {
    int hh = t & 127;
    float a0 = 0.f, a1 = 0.f, ac = 0.f;
    for (int k = 0; k < 128; ++k) {
      float wr = Wrc[k * 128 + hh];
      a0 = fmaf(Wemb[k], wr, a0);
      a1 = fmaf(Wemb[128 + k], wr, a1);
      ac = fmaf(bemb[k], wr, ac);
    }
    r0_s[hh] = a0; r1_s[hh] = a1; rc_s[hh] = ac;
  }
  __syncthreads();
  if (t < 256) {
    int j = t >> 7, hh = t & 127;
    float pg = 0.f;
    for (int k = 0; k < 128; ++k) pg = fmaf(mg_s[j][k], Wqp[k * 128 + hh], pg);
    pg_s[j][hh] = pg;
  } else if (t < 384) {
    int hh = t & 127;
    float pcv = 0.f;
    for (int k = 0; k < 128; ++k) pcv = fmaf(cg_s[k], Wqp[k * 128 + hh], pcv);
    pc_s[hh] = pcv + cp_s[hh];
  } else {
    int hh = t & 127;
    float t0 = 0.f, t1 = 0.f, tc = 0.f;
    for (int k = 0; k < 128; ++k) {
      float w1 = W1[k * 128 + hh];
      t0 = fmaf(r0_s[k], w1, t0);
      t1 = fmaf(r1_s[k], w1, t1);
      tc = fmaf(rc_s[k], w1, tc);
    }
    float4* w4 = (float4*)ws;
    w4[WS_CT / 4 + hh] = make_float4(t0, t1, tc + b1[hh], W2[hh]);
  }
  __syncthreads();
  if (t < 128) {
    float4* w4 = (float4*)ws;
    w4[WS_TG / 4 + t] = make_float4(mg_s[0][t], mg_s[1][t], vg[t], cg_s[t]);
    w4[WS_TP / 4 + t] = make_float4(mp_s[0][t], mp_s[1][t], vp[t], cp_s[t]);
    w4[WS_TQ / 4 + t] = make_float4(pg_s[0][t], pg_s[1][t], pc_s[t], 0.f);
  }
  {
    int j = t;
    float a0 = 0.f, a1 = 0.f, a2 = 0.f, a3 = 0.f;
    for (int k = 0; k < 128; ++k) {
      float wi = Wi[k * G4 + j];
      a0 = fmaf(Wemb[k], wi, a0);
      a1 = fmaf(Wemb[128 + k], wi, a1);
      a2 = fmaf(bemb[k], wi, a2);
      a3 = fmaf(dinit[k], wi, a3);
    }
    ws[WS_A0 + j] = a0;
    ws[WS_A1 + j] = a1;
    ws[WS_A2 + j] = a2 + bl[j];
    ws[WS_A3 + j] = a3 + bl[j];
  }
}

// Persistent: 256 blocks x 1024 threads. Wh+Wqg register-resident; zero
// global reads in the loop. C/E: wave = 8-h chunk x all 4 rows, n per lane;
// tables/q via b128 broadcasts. D/F: DPP reductions, no max-subtract.
__global__ __launch_bounds__(1024, 4) void k_mega(const float* __restrict__ ip,
                                                  const float* __restrict__ Wh,
                                                  const float* __restrict__ Wqg,
                                                  const float* __restrict__ b2,
                                                  const float* __restrict__ ws,
                                                  float* __restrict__ out) {
  __shared__ __align__(16) float gpart[8][4][G4];     // 64 KB
  __shared__ __align__(16) float qpart[8][4][Hd];     // 16 KB
  __shared__ __align__(16) float up_s[16][4][64];     // 16 KB score partials
  __shared__ __align__(16) float q_w[16][32];         // q packed [hp][r]
  __shared__ __align__(16) float qp_s[Hd * 4];        // pointer q [h][r]
  __shared__ __align__(16) float h_s[4][Hd];
  __shared__ __align__(16) float c_s[4][Hd];
  __shared__ __align__(16) float tg_s[G4];
  __shared__ __align__(16) float tp_s[G4];
  __shared__ __align__(16) float tq_s[G4];
  __shared__ __align__(16) float ct_s[G4];
  __shared__ __align__(16) float a0_s[G4], a1_s[G4], a2_s[G4], a3_s[G4];
  __shared__ __align__(16) float cg_s[Hd];
  __shared__ __align__(16) float ip_s[4][Npt * 2];
  __shared__ float mask_s[4][Npt];
  __shared__ float ch_s[4][Npt * 2];
  __shared__ float sel_s[4][2];

  int t = threadIdx.x, blk = blockIdx.x;
  int w = t >> 6, lane = t & 63;
  int kh = t >> 7, jt = t & 127;     // 8 k-chunks x 128 cols

  // ---- register-resident weights ----
  float4 wv[16];                     // Wh[kh*16 .. +16)[jt*4 .. +4)
  #pragma unroll
  for (int j = 0; j < 16; ++j)
    wv[j] = *(const float4*)&Wh[(kh * 16 + j) * G4 + jt * 4];
  float wqr[16];                     // Wqg[kh*16 .. +16)[jt]
  #pragma unroll
  for (int j = 0; j < 16; ++j)
    wqr[j] = Wqg[(kh * 16 + j) * Hd + jt];

  // ---- stage tables + per-block state ----
  if (t < 128) {
    float4 tg4 = ((const float4*)(ws + WS_TG))[t];
    ((float4*)tg_s)[t] = tg4;
    cg_s[t] = tg4.w;
    ((float4*)tp_s)[t] = ((const float4*)(ws + WS_TP))[t];
    ((float4*)tq_s)[t] = ((const float4*)(ws + WS_TQ))[t];
    ((float4*)ct_s)[t] = ((const float4*)(ws + WS_CT))[t];
  } else if (t < 256) {
    int i = t - 128;
    ((float4*)a0_s)[i] = ((const float4*)(ws + WS_A0))[i];
    ((float4*)a1_s)[i] = ((const float4*)(ws + WS_A1))[i];
    ((float4*)a2_s)[i] = ((const float4*)(ws + WS_A2))[i];
    ((float4*)a3_s)[i] = ((const float4*)(ws + WS_A3))[i];
  }
  if (t < 200) {
    ((float2*)ip_s)[t] = ((const float2*)ip)[blk * 200 + t];
    ((float*)mask_s)[t] = 0.f;
  }
  if (t < 512) {
    int r = t >> 7, hh = t & 127;
    h_s[r][hh] = 0.f;
    c_s[r][hh] = 0.f;
  }
  if (t < 8) ((float*)sel_s)[t] = 0.f;
  __syncthreads();

  // per-lane n coords for C/E (constant across steps)
  float2 pn0 = make_float2(0.f, 0.f), pn1 = pn0, pn2 = pn0, pn3 = pn0;
  if (lane < Npt) {
    pn0 = ((float2*)ip_s)[0 * Npt + lane];
    pn1 = ((float2*)ip_s)[1 * Npt + lane];
    pn2 = ((float2*)ip_s)[2 * Npt + lane];
    pn3 = ((float2*)ip_s)[3 * Npt + lane];
  }

  for (int st = 0; st < Tt; ++st) {
    // ---- A1: h @ Wh partials from register weights ----
    {
      int k0 = kh * 16;
      #pragma unroll
      for (int r = 0; r < 4; ++r) {
        float4 ha = *(const float4*)&h_s[r][k0];
        float4 hb = *(const float4*)&h_s[r][k0 + 4];
        float4 hc = *(const float4*)&h_s[r][k0 + 8];
        float4 hd = *(const float4*)&h_s[r][k0 + 12];
        float hv[16] = {ha.x, ha.y, ha.z, ha.w, hb.x, hb.y, hb.z, hb.w,
                        hc.x, hc.y, hc.z, hc.w, hd.x, hd.y, hd.z, hd.w};
        float a0 = 0.f, a1 = 0.f, a2 = 0.f, a3 = 0.f;
        #pragma unroll
        for (int kk = 0; kk < 16; ++kk) {
          float4 wj = wv[kk];
          a0 = fmaf(hv[kk], wj.x, a0);
          a1 = fmaf(hv[kk], wj.y, a1);
          a2 = fmaf(hv[kk], wj.z, a2);
          a3 = fmaf(hv[kk], wj.w, a3);
        }
        *(float4*)&gpart[kh][r][jt * 4] = make_float4(a0, a1, a2, a3);
      }
    }
    __syncthreads();
    // ---- A2: combine + rank-2 x-part + LSTM cell ----
    if (t < 512) {
      int r = t >> 7, hh = t & 127;
      float p0 = sel_s[r][0], p1 = sel_s[r][1];
      float g[4];
      #pragma unroll
      for (int gi = 0; gi < 4; ++gi) {
        int j = gi * 128 + hh;
        float x = (st == 0) ? a3_s[j]
                            : fmaf(p0, a0_s[j], fmaf(p1, a1_s[j], a2_s[j]));
        #pragma unroll
        for (int k8 = 0; k8 < 8; ++k8) x += gpart[k8][r][j];
        g[gi] = x;
      }
      float c2 = fsig(g[1]) * c_s[r][hh] + fsig(g[0]) * ftanh(g[2]);
      float h2 = fsig(g[3]) * ftanh(c2);
      c_s[r][hh] = c2;
      h_s[r][hh] = h2;
    }
    __syncthreads();
    // ---- B: qpart = h2 @ Wqg (k-split 8-way, register weights) ----
    {
      int k0 = kh * 16;
      #pragma unroll
      for (int r = 0; r < 4; ++r) {
        float4 ha = *(const float4*)&h_s[r][k0];
        float4 hb = *(const float4*)&h_s[r][k0 + 4];
        float4 hc = *(const float4*)&h_s[r][k0 + 8];
        float4 hd = *(const float4*)&h_s[r][k0 + 12];
        float hv[16] = {ha.x, ha.y, ha.z, ha.w, hb.x, hb.y, hb.z, hb.w,
                        hc.x, hc.y, hc.z, hc.w, hd.x, hd.y, hd.z, hd.w};
        float a = 0.f;
        #pragma unroll
        for (int kk = 0; kk < 16; ++kk) a = fmaf(hv[kk], wqr[kk], a);
        qpart[kh][r][jt] = a;
      }
    }
    __syncthreads();
    // ---- C: glimpse scores; wave = 8-h chunk x 4 rows, n per lane ----
    {
      if (lane < 32) {                       // fold q-combine into C
        int rr = lane & 3, h = (w << 3) + (lane >> 2);
        float qs = cg_s[h];
        #pragma unroll
        for (int k = 0; k < 8; ++k) qs += qpart[k][rr][h];
        q_w[w][lane] = qs;                   // packed [hp][r]
      }
      float ac0 = 0.f, ac1 = 0.f, ac2 = 0.f, ac3 = 0.f;
      #pragma unroll
      for (int hp = 0; hp < 8; ++hp) {
        float4 tg4 = ((float4*)tg_s)[(w << 3) + hp];
        float4 qr = ((float4*)q_w[w])[hp];
        ac0 = fmaf(tg4.z, ftanh(fmaf(pn0.x, tg4.x, fmaf(pn0.y, tg4.y, qr.x))), ac0);
        ac1 = fmaf(tg4.z, ftanh(fmaf(pn1.x, tg4.x, fmaf(pn1.y, tg4.y, qr.y))), ac1);
        ac2 = fmaf(tg4.z, ftanh(fmaf(pn2.x, tg4.x, fmaf(pn2.y, tg4.y, qr.z))), ac2);
        ac3 = fmaf(tg4.z, ftanh(fmaf(pn3.x, tg4.x, fmaf(pn3.y, tg4.y, qr.w))), ac3);
      }
      up_s[w][0][lane] = ac0;
      up_s[w][1][lane] = ac1;
      up_s[w][2][lane] = ac2;
      up_s[w][3][lane] = ac3;
    }
    __syncthreads();
    // ---- D: glimpse softmax (no max-subtract; u bounded) -> pointer q ----
    if (w < 4) {
      int r = w;
      float u = 0.f;
      #pragma unroll
      for (int c = 0; c < 16; ++c) u += up_s[c][r][lane];
      float2 ipn = make_float2(0.f, 0.f);
      float e = 0.f;
      if (lane < Npt) {
        ipn = ((float2*)ip_s)[r * Npt + lane];
        e = __expf(u - NEGC * mask_s[r][lane]);
      }
      float ssum = dpp_sum_bcast(e);
      float p = e / ssum;
      float s0 = dpp_sum_bcast(p * ipn.x);
      float s1 = dpp_sum_bcast(p * ipn.y);
      float4 tq0 = ((float4*)tq_s)[lane];
      float4 tq1 = ((float4*)tq_s)[64 + lane];
      qp_s[lane * 4 + r]        = fmaf(s0, tq0.x, fmaf(s1, tq0.y, tq0.z));
      qp_s[(64 + lane) * 4 + r] = fmaf(s0, tq1.x, fmaf(s1, tq1.y, tq1.z));
    }
    __syncthreads();
    // ---- E: pointer scores; same tiling as C ----
    {
      float ac0 = 0.f, ac1 = 0.f, ac2 = 0.f, ac3 = 0.f;
      #pragma unroll
      for (int hp = 0; hp < 8; ++hp) {
        float4 tp4 = ((float4*)tp_s)[(w << 3) + hp];
        float4 qr = ((float4*)qp_s)[(w << 3) + hp];   // [h][r] packed
        ac0 = fmaf(tp4.z, ftanh(fmaf(pn0.x, tp4.x, fmaf(pn0.y, tp4.y, qr.x))), ac0);
        ac1 = fmaf(tp4.z, ftanh(fmaf(pn1.x, tp4.x, fmaf(pn1.y, tp4.y, qr.y))), ac1);
        ac2 = fmaf(tp4.z, ftanh(fmaf(pn2.x, tp4.x, fmaf(pn2.y, tp4.y, qr.z))), ac2);
        ac3 = fmaf(tp4.z, ftanh(fmaf(pn3.x, tp4.x, fmaf(pn3.y, tp4.y, qr.w))), ac3);
      }
      up_s[w][0][lane] = ac0;
      up_s[w][1][lane] = ac1;
      up_s[w][2][lane] = ac2;
      up_s[w][3][lane] = ac3;
    }
    __syncthreads();
    // ---- F: logits, softmax/log_softmax (no max-subtract; |logit|<=10),
    //         argmax via dpp-max+ballot, outputs, mask, selection ----
    if (w < 4) {
      int r = w, b = blk * 4 + r;
      float u = 0.f;
      #pragma unroll
      for (int c = 0; c < 16; ++c) u += up_s[c][r][lane];
      float x = 0.f, e = 0.f;
      if (lane < Npt) {
        x = CTANH * ftanh(u) - NEGC * mask_s[r][lane];
        e = __expf(x);
      }
      float ssum = dpp_sum_bcast(e);
      float ls = __logf(ssum);
      float prob = e / ssum;
      if (lane < Npt) {
        out[OFF_LP + ((size_t)b * Tt + st) * Npt + lane] = x - ls;
        out[OFF_P + ((size_t)b * Tt + st) * Npt + lane] = prob;
      }
      float mx = dpp_max_bcast(prob);        // probs >= 0
      unsigned long long bal = __ballot((prob == mx) && (lane < Npt));
      int a = __ffsll(bal) - 1;              // first-index tie-break
      float p0a = ip_s[r][2 * a];
      float p1a = ip_s[r][2 * a + 1];
      if (lane == 0) {
        out[OFF_A + (size_t)b * Tt + st] = (float)a;
        out[OFF_C + ((size_t)b * Tt + st) * 2 + 0] = p0a;
        out[OFF_C + ((size_t)b * Tt + st) * 2 + 1] = p1a;
        ((float2*)ch_s)[r * Npt + st] = make_float2(p0a, p1a);
        mask_s[r][a] = 1.0f;
        sel_s[r][0] = p0a;
        sel_s[r][1] = p1a;
      }
    }
    __syncthreads();
  }

  // ---- epilogue: collapsed critic + tour length ----
  if (w < 4) {
    int r = w, b = blk * 4 + r;
    float p0 = sel_s[r][0], p1 = sel_s[r][1];
    float4 ct0 = ((float4*)ct_s)[lane];
    float4 ct1 = ((float4*)ct_s)[64 + lane];
    float t1a = fmaxf(fmaf(p0, ct0.x, fmaf(p1, ct0.y, ct0.z)), 0.f);
    float t1b = fmaxf(fmaf(p0, ct1.x, fmaf(p1, ct1.y, ct1.z)), 0.f);
    float sv = xsum(t1a * ct0.w + t1b * ct1.w);
    if (lane == 0) out[OFF_V + b] = sv + b2[0];
    float rr = 0.f;
    if (lane < Npt) {
      float2 c0 = ((float2*)ch_s)[r * Npt + lane];
      float2 c1 = ((float2*)ch_s)[r * Npt + ((lane == Npt - 1) ? 0 : lane + 1)];
      float dx = c1.x - c0.x, dy = c1.y - c0.y;
      rr = sqrtf(dx * dx + dy * dy + 1e-10f);
    }
    rr = xsum(rr);
    if (lane == 0) out[OFF_R + b] = rr;
  }
}

extern "C" void kernel_launch(void* const* d_in, const int* in_sizes, int n_in,
                              void* d_out, int out_size, void* d_ws, size_t ws_size,
                              hipStream_t stream) {
  (void)in_sizes; (void)n_in; (void)out_size; (void)ws_size;
  const float* ip    = (const float*)d_in[0];
  const float* Wemb  = (const float*)d_in[1];
  const float* bemb  = (const float*)d_in[2];
  const float* dinit = (const float*)d_in[3];
  const float* Wi    = (const float*)d_in[4];
  const float* Wh    = (const float*)d_in[5];
  const float* bl    = (const float*)d_in[6];
  const float* Wqg   = (const float*)d_in[7];
  const float* Wrg   = (const float*)d_in[8];
  const float* vg    = (const float*)d_in[9];
  const float* Wqp   = (const float*)d_in[10];
  const float* Wrp   = (const float*)d_in[11];
  const float* vp    = (const float*)d_in[12];
  // d_in[13..16], d_in[18] dead: critic N=1 softmax == 1 => hy = e_c
  const float* Wrc   = (const float*)d_in[17];
  const float* W1    = (const float*)d_in[19];
  const float* b1    = (const float*)d_in[20];
  const float* W2    = (const float*)d_in[21];
  const float* b2    = (const float*)d_in[22];
  float* out = (float*)d_out;
  float* ws  = (float*)d_ws;

  k_pre<<<1, 512, 0, stream>>>(Wemb, bemb, dinit, Wi, bl, Wqp, Wrg, Wrp,
                               vg, vp, Wrc, W1, b1, W2, ws);
  k_mega<<<256, 1024, 0, stream>>>(ip, Wh, Wqg, b2, ws, out);
}